// Round 1
// baseline (3636.952 us; speedup 1.0000x reference)
//
#include <hip/hip_runtime.h>
#include <hip/hip_bf16.h>
#include <limits.h>
#include <math.h>

#define F_IN 92
#define H 35
#define HOUT 64
#define NL 3
#define NEG_SLOPE 0.2f

// ---------- helpers ----------
__device__ __forceinline__ int enc_f(float f) {
    int i = __float_as_int(f);
    return i >= 0 ? i : (i ^ 0x7FFFFFFF);  // monotonic float->int map
}
__device__ __forceinline__ float dec_f(int i) {
    return __int_as_float(i >= 0 ? i : (i ^ 0x7FFFFFFF));
}

__global__ void fill_i32_kernel(int* __restrict__ p, int v, int n) {
    int stride = gridDim.x * blockDim.x;
    for (int i = blockIdx.x * blockDim.x + threadIdx.x; i < n; i += stride) p[i] = v;
}

// h[n,j] = sum_k x[n,k] * W[k,j] + b[j]   (W: F_IN x H)
__global__ void embed_kernel(const float* __restrict__ x, const float* __restrict__ W,
                             const float* __restrict__ b, float* __restrict__ h, int N) {
    __shared__ float sW[F_IN * H];
    for (int t = threadIdx.x; t < F_IN * H; t += blockDim.x) sW[t] = W[t];
    __syncthreads();
    int total = N * H;
    int stride = gridDim.x * blockDim.x;
    for (int t = blockIdx.x * blockDim.x + threadIdx.x; t < total; t += stride) {
        int n = t / H, j = t - n * H;
        const float* xr = x + (long)n * F_IN;
        float acc = b[j];
#pragma unroll 4
        for (int k = 0; k < F_IN; ++k) acc += xr[k] * sW[k * H + j];
        h[t] = acc;
    }
}

// out[r,j] = sum_k in[r,k] * W[k,j]   (W: H x H, no bias)
__global__ void lin_kernel(const float* __restrict__ in, const float* __restrict__ W,
                           float* __restrict__ out, int R) {
    __shared__ float sW[H * H];
    for (int t = threadIdx.x; t < H * H; t += blockDim.x) sW[t] = W[t];
    __syncthreads();
    int total = R * H;
    int stride = gridDim.x * blockDim.x;
    for (int t = blockIdx.x * blockDim.x + threadIdx.x; t < total; t += stride) {
        int r = t / H, j = t - r * H;
        const float* ir = in + (long)r * H;
        float acc = 0.f;
#pragma unroll
        for (int k = 0; k < H; ++k) acc += ir[k] * sW[k * H + j];
        out[t] = acc;
    }
}

// s[r] = dot(xl[r,:], att[0:H])
__global__ void att_kernel(const float* __restrict__ xl, const float* __restrict__ att,
                           float* __restrict__ s, int R) {
    __shared__ float sA[H];
    for (int t = threadIdx.x; t < H; t += blockDim.x) sA[t] = att[t];
    __syncthreads();
    int stride = gridDim.x * blockDim.x;
    for (int r = blockIdx.x * blockDim.x + threadIdx.x; r < R; r += stride) {
        const float* xr = xl + (long)r * H;
        float acc = 0.f;
#pragma unroll
        for (int k = 0; k < H; ++k) acc += xr[k] * sA[k];
        s[r] = acc;
    }
}

// degree counts
__global__ void count_kernel(const int* __restrict__ ni, const int* __restrict__ ei,
                             float* __restrict__ Dc, float* __restrict__ Bc, int ninc) {
    int stride = gridDim.x * blockDim.x;
    for (int i = blockIdx.x * blockDim.x + threadIdx.x; i < ninc; i += stride) {
        atomicAdd(&Dc[ni[i]], 1.f);
        atomicAdd(&Bc[ei[i]], 1.f);
    }
}
__global__ void inv_kernel(float* __restrict__ p, int n) {
    int stride = gridDim.x * blockDim.x;
    for (int i = blockIdx.x * blockDim.x + threadIdx.x; i < n; i += stride) {
        float v = p[i];
        p[i] = v > 0.f ? 1.f / v : 0.f;
    }
}

// score = leaky_relu(s_n[ni] + s_e[ei]); segment max by edge (encoded-int atomicMax)
__global__ void score_max_kernel(const int* __restrict__ ni, const int* __restrict__ ei,
                                 const float* __restrict__ s_n, const float* __restrict__ s_e,
                                 float* __restrict__ alpha, int* __restrict__ emax, int ninc) {
    int stride = gridDim.x * blockDim.x;
    for (int i = blockIdx.x * blockDim.x + threadIdx.x; i < ninc; i += stride) {
        float v = s_n[ni[i]] + s_e[ei[i]];
        v = v >= 0.f ? v : NEG_SLOPE * v;
        alpha[i] = v;
        atomicMax(&emax[ei[i]], enc_f(v));
    }
}

__global__ void exp_sum_kernel(const int* __restrict__ ei, const int* __restrict__ emax,
                               float* __restrict__ alpha, float* __restrict__ esum, int ninc) {
    int stride = gridDim.x * blockDim.x;
    for (int i = blockIdx.x * blockDim.x + threadIdx.x; i < ninc; i += stride) {
        int e = ei[i];
        float ex = expf(alpha[i] - dec_f(emax[e]));
        alpha[i] = ex;
        atomicAdd(&esum[e], ex);
    }
}

__global__ void norm_kernel(const int* __restrict__ ei, const float* __restrict__ esum,
                            float* __restrict__ alpha, int ninc) {
    int stride = gridDim.x * blockDim.x;
    for (int i = blockIdx.x * blockDim.x + threadIdx.x; i < ninc; i += stride) {
        alpha[i] = alpha[i] / (esum[ei[i]] + 1e-16f);
    }
}

// e_out[e,j] += Binv[e]*alpha[i] * xl[v,j]
__global__ void scatter1_kernel(const int* __restrict__ ni, const int* __restrict__ ei,
                                const float* __restrict__ alpha, const float* __restrict__ Binv,
                                const float* __restrict__ xl, float* __restrict__ e_out, int ninc) {
    int total = ninc * H;  // 70M fits in int
    int stride = gridDim.x * blockDim.x;
    for (int t = blockIdx.x * blockDim.x + threadIdx.x; t < total; t += stride) {
        int i = t / H, j = t - i * H;
        int e = ei[i], v = ni[i];
        float c = Binv[e] * alpha[i];
        atomicAdd(&e_out[(long)e * H + j], c * xl[(long)v * H + j]);
    }
}

// init accumulator with bias
__global__ void bias_init_kernel(float* __restrict__ h2, const float* __restrict__ b, int N) {
    int total = N * H;
    int stride = gridDim.x * blockDim.x;
    for (int t = blockIdx.x * blockDim.x + threadIdx.x; t < total; t += stride) {
        int j = t - (t / H) * H;
        h2[t] = b[j];
    }
}

// h2[v,j] += Dinv[v]*alpha[i] * e_out[e,j]
__global__ void scatter2_kernel(const int* __restrict__ ni, const int* __restrict__ ei,
                                const float* __restrict__ alpha, const float* __restrict__ Dinv,
                                const float* __restrict__ e_out, float* __restrict__ h2, int ninc) {
    int total = ninc * H;
    int stride = gridDim.x * blockDim.x;
    for (int t = blockIdx.x * blockDim.x + threadIdx.x; t < total; t += stride) {
        int i = t / H, j = t - i * H;
        int e = ei[i], v = ni[i];
        float c = Dinv[v] * alpha[i];
        atomicAdd(&h2[(long)v * H + j], c * e_out[(long)e * H + j]);
    }
}

// scatter-mean pooling accumulation
__global__ void pool_kernel(const float* __restrict__ h, const int* __restrict__ batch,
                            float* __restrict__ pool, float* __restrict__ cnt, int N) {
    int total = N * H;
    int stride = gridDim.x * blockDim.x;
    for (int t = blockIdx.x * blockDim.x + threadIdx.x; t < total; t += stride) {
        int n = t / H, j = t - n * H;
        int g = batch[n];
        atomicAdd(&pool[(long)g * H + j], h[t]);
        if (j == 0) atomicAdd(&cnt[g], 1.f);
    }
}

// head: z = softplus(pooled @ proj_W + proj_b); out = z @ out_W + out_b
__global__ void head_kernel(const float* __restrict__ pool, const float* __restrict__ cnt,
                            const float* __restrict__ pW, const float* __restrict__ pb,
                            const float* __restrict__ oW, const float* __restrict__ ob,
                            float* __restrict__ out) {
    int g = blockIdx.x;
    int j = threadIdx.x;  // 64 threads = 1 wave
    __shared__ float p[H];
    float inv = 1.f / fmaxf(cnt[g], 1.f);
    if (j < H) p[j] = pool[(long)g * H + j] * inv;
    __syncthreads();
    float acc = pb[j];
#pragma unroll
    for (int k = 0; k < H; ++k) acc += p[k] * pW[k * HOUT + j];
    // stable softplus: max(x,0) + log1p(exp(-|x|))
    float z = fmaxf(acc, 0.f) + log1pf(expf(-fabsf(acc)));
    float pr = z * oW[j];
#pragma unroll
    for (int off = 32; off > 0; off >>= 1) pr += __shfl_down(pr, off);
    if (j == 0) out[g] = pr + ob[0];
}

static inline int grid_for(long n, int block = 256, long cap = 2048) {
    long b = (n + block - 1) / block;
    if (b > cap) b = cap;
    if (b < 1) b = 1;
    return (int)b;
}

extern "C" void kernel_launch(void* const* d_in, const int* in_sizes, int n_in,
                              void* d_out, int out_size, void* d_ws, size_t ws_size,
                              hipStream_t stream) {
    const float* x       = (const float*)d_in[0];
    const float* he      = (const float*)d_in[1];
    const int*   ni      = (const int*)d_in[2];
    const int*   ei      = (const int*)d_in[3];
    const int*   batch   = (const int*)d_in[4];
    const float* embed_W = (const float*)d_in[5];
    const float* embed_b = (const float*)d_in[6];
    const float* lin_W   = (const float*)d_in[7];   // [L,H,H]
    const float* att     = (const float*)d_in[8];   // [L,2H]
    const float* conv_b  = (const float*)d_in[9];   // [L,H]
    const float* proj_W  = (const float*)d_in[10];  // [H,HOUT]
    const float* proj_b  = (const float*)d_in[11];
    const float* out_W   = (const float*)d_in[12];  // [HOUT,1]
    const float* out_b   = (const float*)d_in[13];
    float* out = (float*)d_out;

    const int N    = in_sizes[0] / F_IN;  // 100000
    const int E    = in_sizes[1] / H;     // 50000
    const int NINC = in_sizes[2];         // 2000000
    const int G    = out_size;            // 256

    // workspace carve-up
    char* w = (char*)d_ws;
    auto alloc = [&](size_t bytes) {
        char* p = w;
        w += (bytes + 255) & ~(size_t)255;
        return p;
    };
    float* hA    = (float*)alloc((size_t)N * H * 4);
    float* hB    = (float*)alloc((size_t)N * H * 4);
    float* xl    = (float*)alloc((size_t)N * H * 4);
    float* el    = (float*)alloc((size_t)E * H * 4);
    float* e_out = (float*)alloc((size_t)E * H * 4);
    float* s_n   = (float*)alloc((size_t)N * 4);
    float* s_e   = (float*)alloc((size_t)E * 4);
    int*   emax  = (int*)  alloc((size_t)E * 4);
    float* esum  = (float*)alloc((size_t)E * 4);
    float* alpha = (float*)alloc((size_t)NINC * 4);
    float* Binv  = (float*)alloc((size_t)E * 4);
    float* Dinv  = (float*)alloc((size_t)N * 4);
    float* pool  = (float*)alloc((size_t)G * H * 4);
    float* cnt   = (float*)alloc((size_t)G * 4);

    const int BLK = 256;
    int gNH   = grid_for((long)N * H);
    int gEH   = grid_for((long)E * H);
    int gNI   = grid_for(NINC);
    int gNIH  = grid_for((long)NINC * H);
    int gN    = grid_for(N);
    int gE    = grid_for(E);

    // degrees (same for all layers)
    hipMemsetAsync(Dinv, 0, (size_t)N * 4, stream);
    hipMemsetAsync(Binv, 0, (size_t)E * 4, stream);
    count_kernel<<<gNI, BLK, 0, stream>>>(ni, ei, Dinv, Binv, NINC);
    inv_kernel<<<gN, BLK, 0, stream>>>(Dinv, N);
    inv_kernel<<<gE, BLK, 0, stream>>>(Binv, E);

    // embed
    embed_kernel<<<gNH, BLK, 0, stream>>>(x, embed_W, embed_b, hA, N);

    float* hcur = hA;
    float* hnext = hB;
    for (int l = 0; l < NL; ++l) {
        const float* W  = lin_W + (size_t)l * H * H;
        const float* at = att + (size_t)l * 2 * H;
        const float* b  = conv_b + (size_t)l * H;

        lin_kernel<<<gNH, BLK, 0, stream>>>(hcur, W, xl, N);
        lin_kernel<<<gEH, BLK, 0, stream>>>(he, W, el, E);
        att_kernel<<<gN, BLK, 0, stream>>>(xl, at, s_n, N);
        att_kernel<<<gE, BLK, 0, stream>>>(el, at + H, s_e, E);

        fill_i32_kernel<<<gE, BLK, 0, stream>>>(emax, INT_MIN, E);
        hipMemsetAsync(esum, 0, (size_t)E * 4, stream);
        score_max_kernel<<<gNI, BLK, 0, stream>>>(ni, ei, s_n, s_e, alpha, emax, NINC);
        exp_sum_kernel<<<gNI, BLK, 0, stream>>>(ei, emax, alpha, esum, NINC);
        norm_kernel<<<gNI, BLK, 0, stream>>>(ei, esum, alpha, NINC);

        hipMemsetAsync(e_out, 0, (size_t)E * H * 4, stream);
        scatter1_kernel<<<gNIH, BLK, 0, stream>>>(ni, ei, alpha, Binv, xl, e_out, NINC);
        bias_init_kernel<<<gNH, BLK, 0, stream>>>(hnext, b, N);
        scatter2_kernel<<<gNIH, BLK, 0, stream>>>(ni, ei, alpha, Dinv, e_out, hnext, NINC);

        float* tmp = hcur; hcur = hnext; hnext = tmp;
    }

    // pooling + head
    hipMemsetAsync(pool, 0, (size_t)G * H * 4, stream);
    hipMemsetAsync(cnt, 0, (size_t)G * 4, stream);
    pool_kernel<<<gNH, BLK, 0, stream>>>(hcur, batch, pool, cnt, N);
    head_kernel<<<G, 64, 0, stream>>>(pool, cnt, proj_W, proj_b, out_W, out_b, out);
}

// Round 2
// 2229.595 us; speedup vs baseline: 1.6312x; 1.6312x over previous
//
#include <hip/hip_runtime.h>
#include <hip/hip_bf16.h>
#include <limits.h>
#include <math.h>

#define F_IN 92
#define H 35
#define HOUT 64
#define NL 3
#define NEG_SLOPE 0.2f

// ------------------------------------------------------------------
// dense kernels
// ------------------------------------------------------------------

// h[n,j] = sum_k x[n,k] * W[k,j] + b[j]   (W: F_IN x H)
__global__ void embed_kernel(const float* __restrict__ x, const float* __restrict__ W,
                             const float* __restrict__ b, float* __restrict__ h, int N) {
    __shared__ float sW[F_IN * H];
    for (int t = threadIdx.x; t < F_IN * H; t += blockDim.x) sW[t] = W[t];
    __syncthreads();
    int total = N * H;
    int stride = gridDim.x * blockDim.x;
    for (int t = blockIdx.x * blockDim.x + threadIdx.x; t < total; t += stride) {
        int n = t / H, j = t - n * H;
        const float* xr = x + (long)n * F_IN;
        float acc = b[j];
#pragma unroll 4
        for (int k = 0; k < F_IN; ++k) acc += xr[k] * sW[k * H + j];
        h[t] = acc;
    }
}

// out[r,j] = sum_k in[r,k] * W[k,j]   (W: H x H, no bias)
__global__ void lin_kernel(const float* __restrict__ in, const float* __restrict__ W,
                           float* __restrict__ out, int R) {
    __shared__ float sW[H * H];
    for (int t = threadIdx.x; t < H * H; t += blockDim.x) sW[t] = W[t];
    __syncthreads();
    int total = R * H;
    int stride = gridDim.x * blockDim.x;
    for (int t = blockIdx.x * blockDim.x + threadIdx.x; t < total; t += stride) {
        int r = t / H, j = t - r * H;
        const float* ir = in + (long)r * H;
        float acc = 0.f;
#pragma unroll
        for (int k = 0; k < H; ++k) acc += ir[k] * sW[k * H + j];
        out[t] = acc;
    }
}

// s[r] = dot(in[r,:], vec[0:H])
__global__ void rowdot_kernel(const float* __restrict__ in, const float* __restrict__ vec,
                              float* __restrict__ s, int R) {
    __shared__ float sA[H];
    for (int t = threadIdx.x; t < H; t += blockDim.x) sA[t] = vec[t];
    __syncthreads();
    int stride = gridDim.x * blockDim.x;
    for (int r = blockIdx.x * blockDim.x + threadIdx.x; r < R; r += stride) {
        const float* xr = in + (long)r * H;
        float acc = 0.f;
#pragma unroll
        for (int k = 0; k < H; ++k) acc += xr[k] * sA[k];
        s[r] = acc;
    }
}

// w2[k] = sum_j W[k,j] * a[j]   (tiny: folds lin+att on hyperedge_attr)
__global__ void wfold_kernel(const float* __restrict__ W, const float* __restrict__ a,
                             float* __restrict__ w2) {
    int k = threadIdx.x;
    if (k < H) {
        float acc = 0.f;
#pragma unroll
        for (int j = 0; j < H; ++j) acc += W[k * H + j] * a[j];
        w2[k] = acc;
    }
}

// ------------------------------------------------------------------
// CSR build (indices identical across layers -> built once)
// ------------------------------------------------------------------

__global__ void count_int_kernel(const int* __restrict__ ni, const int* __restrict__ ei,
                                 int* __restrict__ ncnt, int* __restrict__ ecnt, int ninc) {
    int stride = gridDim.x * blockDim.x;
    for (int i = blockIdx.x * blockDim.x + threadIdx.x; i < ninc; i += stride) {
        atomicAdd(&ncnt[ni[i]], 1);
        atomicAdd(&ecnt[ei[i]], 1);
    }
}

// exclusive scan of cnt[0..n) into ptr[0..n], single block of 1024 threads
__global__ void scan_kernel(const int* __restrict__ cnt, int* __restrict__ ptr, int n) {
    __shared__ int part[1024];
    int t = threadIdx.x;
    int chunk = (n + 1023) / 1024;
    int lo = t * chunk;
    int hi = lo + chunk; if (hi > n) hi = n; if (lo > n) lo = n;
    int s = 0;
    for (int i = lo; i < hi; ++i) s += cnt[i];
    part[t] = s;
    __syncthreads();
    for (int off = 1; off < 1024; off <<= 1) {
        int v = (t >= off) ? part[t - off] : 0;
        __syncthreads();
        part[t] += v;
        __syncthreads();
    }
    int base = (t == 0) ? 0 : part[t - 1];
    for (int i = lo; i < hi; ++i) { ptr[i] = base; base += cnt[i]; }
    if (t == 1023) ptr[n] = part[1023];
}

// counting-sort fill: edge-CSR stores node ids, node-CSR stores edge ids
__global__ void csr_fill_kernel(const int* __restrict__ ni, const int* __restrict__ ei,
                                int* __restrict__ ecur, int* __restrict__ ncur,
                                int* __restrict__ enode, int* __restrict__ nedge, int ninc) {
    int stride = gridDim.x * blockDim.x;
    for (int i = blockIdx.x * blockDim.x + threadIdx.x; i < ninc; i += stride) {
        int v = ni[i], e = ei[i];
        int p = atomicAdd(&ecur[e], 1); enode[p] = v;
        int q = atomicAdd(&ncur[v], 1); nedge[q] = e;
    }
}

// ------------------------------------------------------------------
// fused sparse passes (atomic-free, 1 wave per segment)
// ------------------------------------------------------------------

// per edge e: softmax over incident nodes + weighted accumulation into e_out[e,:]
// stores em[e] (softmax max) and erec[e] = 1/(sum+1e-16) for recompute in node_pass
__global__ void edge_pass_kernel(const int* __restrict__ eptr, const int* __restrict__ enode,
                                 const float* __restrict__ s_n, const float* __restrict__ s_e,
                                 const float* __restrict__ xl,
                                 float* __restrict__ e_out, float* __restrict__ em,
                                 float* __restrict__ erec, int E) {
    int lane = threadIdx.x & 63;
    int wid = (blockIdx.x * blockDim.x + threadIdx.x) >> 6;
    int nw = (gridDim.x * blockDim.x) >> 6;
    for (int e = wid; e < E; e += nw) {
        int lo = eptr[e], hi = eptr[e + 1];
        float se = s_e[e];
        // pass 1: segment max (lane-parallel)
        float m = -INFINITY;
        for (int k = lo + lane; k < hi; k += 64) {
            float sc = s_n[enode[k]] + se;
            sc = sc >= 0.f ? sc : NEG_SLOPE * sc;
            m = fmaxf(m, sc);
        }
#pragma unroll
        for (int off = 32; off; off >>= 1) m = fmaxf(m, __shfl_xor(m, off));
        float mm = (m == -INFINITY) ? 0.f : m;
        // pass 2: sum of exp (lane-parallel)
        float s = 0.f;
        for (int k = lo + lane; k < hi; k += 64) {
            float sc = s_n[enode[k]] + se;
            sc = sc >= 0.f ? sc : NEG_SLOPE * sc;
            s += expf(sc - mm);
        }
#pragma unroll
        for (int off = 32; off; off >>= 1) s += __shfl_xor(s, off);
        float rec = 1.f / (s + 1e-16f);
        // pass 3: e_out[e,j] = sum_i Binv * alpha_i * xl[v_i, j]  (lane j holds col j)
        float binv = (hi > lo) ? 1.f / (float)(hi - lo) : 0.f;
        float cb = binv * rec;
        float acc = 0.f;
#pragma unroll 2
        for (int k = lo; k < hi; ++k) {
            int v = enode[k];                 // broadcast load
            float sc = s_n[v] + se;           // broadcast load
            sc = sc >= 0.f ? sc : NEG_SLOPE * sc;
            float a = expf(sc - mm) * cb;
            if (lane < H) acc += a * xl[(long)v * H + lane];
        }
        if (lane < H) e_out[(long)e * H + lane] = acc;
        if (lane == 0) { em[e] = mm; erec[e] = rec; }
    }
}

// per node v: h[v,j] = Dinv * sum_i alpha_i * e_out[e_i, j] + bias[j]
__global__ void node_pass_kernel(const int* __restrict__ nptr, const int* __restrict__ nedge,
                                 const float* __restrict__ s_n, const float* __restrict__ s_e,
                                 const float* __restrict__ em, const float* __restrict__ erec,
                                 const float* __restrict__ e_out, const float* __restrict__ bias,
                                 float* __restrict__ hout, int N) {
    int lane = threadIdx.x & 63;
    int wid = (blockIdx.x * blockDim.x + threadIdx.x) >> 6;
    int nw = (gridDim.x * blockDim.x) >> 6;
    for (int v = wid; v < N; v += nw) {
        int lo = nptr[v], hi = nptr[v + 1];
        float dinv = (hi > lo) ? 1.f / (float)(hi - lo) : 0.f;
        float sn = s_n[v];
        float acc = 0.f;
#pragma unroll 2
        for (int k = lo; k < hi; ++k) {
            int e = nedge[k];                 // broadcast load
            float sc = sn + s_e[e];
            sc = sc >= 0.f ? sc : NEG_SLOPE * sc;
            float a = expf(sc - em[e]) * erec[e];
            if (lane < H) acc += a * e_out[(long)e * H + lane];
        }
        if (lane < H) hout[(long)v * H + lane] = dinv * acc + bias[lane];
    }
}

// ------------------------------------------------------------------
// fused pooling (batch sorted -> binary search) + MLP head
// ------------------------------------------------------------------
__global__ void pool_head_kernel(const float* __restrict__ h, const int* __restrict__ batch,
                                 int N, const float* __restrict__ pW, const float* __restrict__ pb,
                                 const float* __restrict__ oW, const float* __restrict__ ob,
                                 float* __restrict__ out) {
    int g = blockIdx.x;
    int t = threadIdx.x;
    __shared__ int bounds[2];
    __shared__ float partial[7][H];
    __shared__ float pooled[H];
    if (t == 0) {
        // lower_bound(batch, g)
        int lo = 0, hi = N;
        while (lo < hi) { int mid = (lo + hi) >> 1; if (batch[mid] < g) lo = mid + 1; else hi = mid; }
        bounds[0] = lo;
        int lo2 = lo, hi2 = N;
        while (lo2 < hi2) { int mid = (lo2 + hi2) >> 1; if (batch[mid] < g + 1) lo2 = mid + 1; else hi2 = mid; }
        bounds[1] = lo2;
    }
    __syncthreads();
    int rlo = bounds[0], rhi = bounds[1];
    int cntg = rhi - rlo;
    // 7 groups x 35 lanes accumulate rows strided by 7
    int gg = t / H;        // 0..6 for t<245
    int j = t - gg * H;
    if (gg < 7) {
        float acc = 0.f;
        for (int r = rlo + gg; r < rhi; r += 7) acc += h[(long)r * H + j];
        partial[gg][j] = acc;
    }
    __syncthreads();
    if (t < H) {
        float s = 0.f;
#pragma unroll
        for (int k = 0; k < 7; ++k) s += partial[k][t];
        pooled[t] = s / fmaxf((float)cntg, 1.f);
    }
    __syncthreads();
    // head on wave 0
    if (t < HOUT) {
        float acc = pb[t];
#pragma unroll
        for (int k = 0; k < H; ++k) acc += pooled[k] * pW[k * HOUT + t];
        float z = fmaxf(acc, 0.f) + log1pf(expf(-fabsf(acc)));  // softplus
        float pr = z * oW[t];
#pragma unroll
        for (int off = 32; off; off >>= 1) pr += __shfl_down(pr, off);
        if (t == 0) out[g] = pr + ob[0];
    }
}

static inline int grid_for(long n, int block = 256, long cap = 2048) {
    long b = (n + block - 1) / block;
    if (b > cap) b = cap;
    if (b < 1) b = 1;
    return (int)b;
}

extern "C" void kernel_launch(void* const* d_in, const int* in_sizes, int n_in,
                              void* d_out, int out_size, void* d_ws, size_t ws_size,
                              hipStream_t stream) {
    const float* x       = (const float*)d_in[0];
    const float* he      = (const float*)d_in[1];
    const int*   ni      = (const int*)d_in[2];
    const int*   ei      = (const int*)d_in[3];
    const int*   batch   = (const int*)d_in[4];
    const float* embed_W = (const float*)d_in[5];
    const float* embed_b = (const float*)d_in[6];
    const float* lin_W   = (const float*)d_in[7];   // [L,H,H]
    const float* att     = (const float*)d_in[8];   // [L,2H]
    const float* conv_b  = (const float*)d_in[9];   // [L,H]
    const float* proj_W  = (const float*)d_in[10];  // [H,HOUT]
    const float* proj_b  = (const float*)d_in[11];
    const float* out_W   = (const float*)d_in[12];  // [HOUT,1]
    const float* out_b   = (const float*)d_in[13];
    float* out = (float*)d_out;

    const int N    = in_sizes[0] / F_IN;  // 100000
    const int E    = in_sizes[1] / H;     // 50000
    const int NINC = in_sizes[2];         // 2000000
    const int G    = out_size;            // 256

    // workspace carve-up
    char* w = (char*)d_ws;
    auto alloc = [&](size_t bytes) {
        char* p = w;
        w += (bytes + 255) & ~(size_t)255;
        return p;
    };
    float* h     = (float*)alloc((size_t)N * H * 4);      // node features (ping)
    float* xl    = (float*)alloc((size_t)N * H * 4);      // lin(h) (pong)
    float* e_out = (float*)alloc((size_t)E * H * 4);
    float* s_n   = (float*)alloc((size_t)N * 4);
    float* s_e   = (float*)alloc((size_t)E * 4);
    float* em    = (float*)alloc((size_t)E * 4);
    float* erec  = (float*)alloc((size_t)E * 4);
    float* w2    = (float*)alloc((size_t)H * 4);
    int*   ecnt  = (int*)alloc((size_t)E * 4);
    int*   eptr  = (int*)alloc((size_t)(E + 1) * 4);
    int*   ecur  = (int*)alloc((size_t)E * 4);
    int*   ncnt  = (int*)alloc((size_t)N * 4);
    int*   nptr  = (int*)alloc((size_t)(N + 1) * 4);
    int*   ncur  = (int*)alloc((size_t)N * 4);
    int*   enode = (int*)alloc((size_t)NINC * 4);
    int*   nedge = (int*)alloc((size_t)NINC * 4);

    const int BLK = 256;
    int gNH  = grid_for((long)N * H);
    int gNI  = grid_for(NINC);
    int gN   = grid_for(N);
    int gE   = grid_for(E);

    // ---- CSR build (once; same incidence structure for all layers) ----
    hipMemsetAsync(ncnt, 0, (size_t)N * 4, stream);
    hipMemsetAsync(ecnt, 0, (size_t)E * 4, stream);
    count_int_kernel<<<gNI, BLK, 0, stream>>>(ni, ei, ncnt, ecnt, NINC);
    scan_kernel<<<1, 1024, 0, stream>>>(ecnt, eptr, E);
    scan_kernel<<<1, 1024, 0, stream>>>(ncnt, nptr, N);
    hipMemcpyAsync(ecur, eptr, (size_t)E * 4, hipMemcpyDeviceToDevice, stream);
    hipMemcpyAsync(ncur, nptr, (size_t)N * 4, hipMemcpyDeviceToDevice, stream);
    csr_fill_kernel<<<gNI, BLK, 0, stream>>>(ni, ei, ecur, ncur, enode, nedge, NINC);

    // ---- embed ----
    embed_kernel<<<gNH, BLK, 0, stream>>>(x, embed_W, embed_b, h, N);

    // ---- layers ----
    int gEdge = (E + 3) / 4;   // 4 waves per 256-block, 1 wave per edge
    int gNode = (N + 3) / 4;
    for (int l = 0; l < NL; ++l) {
        const float* W  = lin_W + (size_t)l * H * H;
        const float* at = att + (size_t)l * 2 * H;
        const float* b  = conv_b + (size_t)l * H;

        lin_kernel<<<gNH, BLK, 0, stream>>>(h, W, xl, N);
        rowdot_kernel<<<gN, BLK, 0, stream>>>(xl, at, s_n, N);
        wfold_kernel<<<1, 64, 0, stream>>>(W, at + H, w2);
        rowdot_kernel<<<gE, BLK, 0, stream>>>(he, w2, s_e, E);

        edge_pass_kernel<<<gEdge, BLK, 0, stream>>>(eptr, enode, s_n, s_e, xl,
                                                    e_out, em, erec, E);
        node_pass_kernel<<<gNode, BLK, 0, stream>>>(nptr, nedge, s_n, s_e, em, erec,
                                                    e_out, b, h, N);
    }

    // ---- pooling + head ----
    pool_head_kernel<<<G, BLK, 0, stream>>>(h, batch, N, proj_W, proj_b, out_W, out_b, out);
}

// Round 4
// 1821.951 us; speedup vs baseline: 1.9962x; 1.2237x over previous
//
#include <hip/hip_runtime.h>
#include <hip/hip_bf16.h>
#include <limits.h>
#include <math.h>

#define F_IN 92
#define H 35
#define HOUT 64
#define NL 3
#define NEG_SLOPE 0.2f

// ------------------------------------------------------------------
// dense kernels
// ------------------------------------------------------------------

// h[n,j] = sum_k x[n,k] * W[k,j] + b[j]   (W: F_IN x H)
__global__ void embed_kernel(const float* __restrict__ x, const float* __restrict__ W,
                             const float* __restrict__ b, float* __restrict__ h, int N) {
    __shared__ float sW[F_IN * H];
    for (int t = threadIdx.x; t < F_IN * H; t += blockDim.x) sW[t] = W[t];
    __syncthreads();
    int total = N * H;
    int stride = gridDim.x * blockDim.x;
    for (int t = blockIdx.x * blockDim.x + threadIdx.x; t < total; t += stride) {
        int n = t / H, j = t - n * H;
        const float* xr = x + (long)n * F_IN;
        float acc = b[j];
#pragma unroll 4
        for (int k = 0; k < F_IN; ++k) acc += xr[k] * sW[k * H + j];
        h[t] = acc;
    }
}

// out[r,j] = sum_k in[r,k] * W[k,j]   (W: H x H, no bias)
__global__ void lin_kernel(const float* __restrict__ in, const float* __restrict__ W,
                           float* __restrict__ out, int R) {
    __shared__ float sW[H * H];
    for (int t = threadIdx.x; t < H * H; t += blockDim.x) sW[t] = W[t];
    __syncthreads();
    int total = R * H;
    int stride = gridDim.x * blockDim.x;
    for (int t = blockIdx.x * blockDim.x + threadIdx.x; t < total; t += stride) {
        int r = t / H, j = t - r * H;
        const float* ir = in + (long)r * H;
        float acc = 0.f;
#pragma unroll
        for (int k = 0; k < H; ++k) acc += ir[k] * sW[k * H + j];
        out[t] = acc;
    }
}

// s[r] = dot(in[r,:], vec[0:H])  -> s[r*stride_out]
__global__ void rowdot_kernel(const float* __restrict__ in, const float* __restrict__ vec,
                              float* __restrict__ s, int R, int stride_out) {
    __shared__ float sA[H];
    for (int t = threadIdx.x; t < H; t += blockDim.x) sA[t] = vec[t];
    __syncthreads();
    int stride = gridDim.x * blockDim.x;
    for (int r = blockIdx.x * blockDim.x + threadIdx.x; r < R; r += stride) {
        const float* xr = in + (long)r * H;
        float acc = 0.f;
#pragma unroll
        for (int k = 0; k < H; ++k) acc += xr[k] * sA[k];
        s[(long)r * stride_out] = acc;
    }
}

// w2[k] = sum_j W[k,j] * a[j]   (tiny: folds lin+att on hyperedge_attr)
__global__ void wfold_kernel(const float* __restrict__ W, const float* __restrict__ a,
                             float* __restrict__ w2) {
    int k = threadIdx.x;
    if (k < H) {
        float acc = 0.f;
#pragma unroll
        for (int j = 0; j < H; ++j) acc += W[k * H + j] * a[j];
        w2[k] = acc;
    }
}

// ------------------------------------------------------------------
// CSR build (indices identical across layers -> built once)
// ------------------------------------------------------------------

__global__ void count_int_kernel(const int* __restrict__ ni, const int* __restrict__ ei,
                                 int* __restrict__ ncnt, int* __restrict__ ecnt, int ninc) {
    int stride = gridDim.x * blockDim.x;
    for (int i = blockIdx.x * blockDim.x + threadIdx.x; i < ninc; i += stride) {
        atomicAdd(&ncnt[ni[i]], 1);
        atomicAdd(&ecnt[ei[i]], 1);
    }
}

// exclusive scan of cnt[0..n) into ptr[0..n], single block of 1024 threads
__global__ void scan_kernel(const int* __restrict__ cnt, int* __restrict__ ptr, int n) {
    __shared__ int part[1024];
    int t = threadIdx.x;
    int chunk = (n + 1023) / 1024;
    int lo = t * chunk;
    int hi = lo + chunk; if (hi > n) hi = n; if (lo > n) lo = n;
    int s = 0;
    for (int i = lo; i < hi; ++i) s += cnt[i];
    part[t] = s;
    __syncthreads();
    for (int off = 1; off < 1024; off <<= 1) {
        int v = (t >= off) ? part[t - off] : 0;
        __syncthreads();
        part[t] += v;
        __syncthreads();
    }
    int base = (t == 0) ? 0 : part[t - 1];
    for (int i = lo; i < hi; ++i) { ptr[i] = base; base += cnt[i]; }
    if (t == 1023) ptr[n] = part[1023];
}

// counting-sort fill: edge-CSR stores node ids, node-CSR stores edge ids
__global__ void csr_fill_kernel(const int* __restrict__ ni, const int* __restrict__ ei,
                                int* __restrict__ ecur, int* __restrict__ ncur,
                                int* __restrict__ enode, int* __restrict__ nedge, int ninc) {
    int stride = gridDim.x * blockDim.x;
    for (int i = blockIdx.x * blockDim.x + threadIdx.x; i < ninc; i += stride) {
        int v = ni[i], e = ei[i];
        int p = atomicAdd(&ecur[e], 1); enode[p] = v;
        int q = atomicAdd(&ncur[v], 1); nedge[q] = e;
    }
}

// ------------------------------------------------------------------
// fused sparse passes (atomic-free, 1 wave per segment, single-load)
// ------------------------------------------------------------------

__device__ __forceinline__ float wave_max(float m) {
#pragma unroll
    for (int off = 32; off; off >>= 1) m = fmaxf(m, __shfl_xor(m, off));
    return m;
}
__device__ __forceinline__ float wave_sum(float s) {
#pragma unroll
    for (int off = 32; off; off >>= 1) s += __shfl_xor(s, off);
    return s;
}

// per edge e: softmax over incident nodes + weighted accumulation into e_out[e,:]
// epack[e] = {s_e, m, 1/(sum+eps), -}; reads epack.x, writes .y/.z
__global__ void edge_pass_kernel(const int* __restrict__ eptr, const int* __restrict__ enode,
                                 const float* __restrict__ s_n, float* __restrict__ epack,
                                 const float* __restrict__ xl,
                                 float* __restrict__ e_out, int E) {
    int lane = threadIdx.x & 63;
    int wid = (blockIdx.x * blockDim.x + threadIdx.x) >> 6;
    int nw = (gridDim.x * blockDim.x) >> 6;
    for (int e = wid; e < E; e += nw) {
        int lo = eptr[e], hi = eptr[e + 1];
        int deg = hi - lo;
        float se = epack[4 * (long)e];
        float binv = deg > 0 ? 1.f / (float)deg : 0.f;
        float acc = 0.f;
        float mm, rec;
        if (deg <= 64) {
            // single lane-parallel load of the whole segment
            int v = 0; float sc = -INFINITY;
            if (lane < deg) {
                v = enode[lo + lane];
                sc = s_n[v] + se;
                sc = sc >= 0.f ? sc : NEG_SLOPE * sc;
            }
            float m = wave_max(sc);
            mm = (m == -INFINITY) ? 0.f : m;
            float ex = (lane < deg) ? expf(sc - mm) : 0.f;
            float s = wave_sum(ex);
            rec = 1.f / (s + 1e-16f);
            float a = ex * rec * binv;
            // serial broadcast gather (uniform index -> readlane; loads pipeline)
#pragma unroll 4
            for (int k = 0; k < deg; ++k) {
                float ak = __shfl(a, k);
                int vk = __shfl(v, k);
                if (lane < H) acc += ak * xl[(long)vk * H + lane];
            }
        } else {
            float m = -INFINITY;
            for (int k = lo + lane; k < hi; k += 64) {
                float sc = s_n[enode[k]] + se;
                sc = sc >= 0.f ? sc : NEG_SLOPE * sc;
                m = fmaxf(m, sc);
            }
            m = wave_max(m);
            mm = (m == -INFINITY) ? 0.f : m;
            float s = 0.f;
            for (int k = lo + lane; k < hi; k += 64) {
                float sc = s_n[enode[k]] + se;
                sc = sc >= 0.f ? sc : NEG_SLOPE * sc;
                s += expf(sc - mm);
            }
            s = wave_sum(s);
            rec = 1.f / (s + 1e-16f);
            float cb = rec * binv;
            for (int base = lo; base < hi; base += 64) {
                int v = 0; float a = 0.f;
                if (base + lane < hi) {
                    v = enode[base + lane];
                    float sc = s_n[v] + se;
                    sc = sc >= 0.f ? sc : NEG_SLOPE * sc;
                    a = expf(sc - mm) * cb;
                }
                int cn = hi - base; if (cn > 64) cn = 64;
#pragma unroll 4
                for (int k = 0; k < cn; ++k) {
                    float ak = __shfl(a, k);
                    int vk = __shfl(v, k);
                    if (lane < H) acc += ak * xl[(long)vk * H + lane];
                }
            }
        }
        if (lane < H) e_out[(long)e * H + lane] = acc;
        if (lane == 0) { epack[4 * (long)e + 1] = mm; epack[4 * (long)e + 2] = rec; }
    }
}

// per node v: h[v,j] = Dinv * sum_i alpha_i * e_out[e_i, j] + bias[j]
__global__ void node_pass_kernel(const int* __restrict__ nptr, const int* __restrict__ nedge,
                                 const float* __restrict__ s_n, const float* __restrict__ epack,
                                 const float* __restrict__ e_out, const float* __restrict__ bias,
                                 float* __restrict__ hout, int N) {
    int lane = threadIdx.x & 63;
    int wid = (blockIdx.x * blockDim.x + threadIdx.x) >> 6;
    int nw = (gridDim.x * blockDim.x) >> 6;
    for (int v = wid; v < N; v += nw) {
        int lo = nptr[v], hi = nptr[v + 1];
        int deg = hi - lo;
        float dinv = deg > 0 ? 1.f / (float)deg : 0.f;
        float sn = s_n[v];
        float acc = 0.f;
        if (deg <= 64) {
            int e = 0; float a = 0.f;
            if (lane < deg) {
                e = nedge[lo + lane];
                float4 p = ((const float4*)epack)[e];   // {s_e, m, rec, -} one 16B gather
                float sc = sn + p.x;
                sc = sc >= 0.f ? sc : NEG_SLOPE * sc;
                a = expf(sc - p.y) * p.z;
            }
#pragma unroll 4
            for (int k = 0; k < deg; ++k) {
                float ak = __shfl(a, k);
                int ek = __shfl(e, k);
                if (lane < H) acc += ak * e_out[(long)ek * H + lane];
            }
        } else {
            for (int base = lo; base < hi; base += 64) {
                int e = 0; float a = 0.f;
                if (base + lane < hi) {
                    e = nedge[base + lane];
                    float4 p = ((const float4*)epack)[e];
                    float sc = sn + p.x;
                    sc = sc >= 0.f ? sc : NEG_SLOPE * sc;
                    a = expf(sc - p.y) * p.z;
                }
                int cn = hi - base; if (cn > 64) cn = 64;
#pragma unroll 4
                for (int k = 0; k < cn; ++k) {
                    float ak = __shfl(a, k);
                    int ek = __shfl(e, k);
                    if (lane < H) acc += ak * e_out[(long)ek * H + lane];
                }
            }
        }
        if (lane < H) hout[(long)v * H + lane] = dinv * acc + bias[lane];
    }
}

// ------------------------------------------------------------------
// fused pooling (batch sorted -> binary search) + MLP head
// ------------------------------------------------------------------
__global__ void pool_head_kernel(const float* __restrict__ h, const int* __restrict__ batch,
                                 int N, const float* __restrict__ pW, const float* __restrict__ pb,
                                 const float* __restrict__ oW, const float* __restrict__ ob,
                                 float* __restrict__ out) {
    int g = blockIdx.x;
    int t = threadIdx.x;
    __shared__ int bounds[2];
    __shared__ float partial[7][H];
    __shared__ float pooled[H];
    if (t == 0) {
        int lo = 0, hi = N;
        while (lo < hi) { int mid = (lo + hi) >> 1; if (batch[mid] < g) lo = mid + 1; else hi = mid; }
        bounds[0] = lo;
        int lo2 = lo, hi2 = N;
        while (lo2 < hi2) { int mid = (lo2 + hi2) >> 1; if (batch[mid] < g + 1) lo2 = mid + 1; else hi2 = mid; }
        bounds[1] = lo2;
    }
    __syncthreads();
    int rlo = bounds[0], rhi = bounds[1];
    int cntg = rhi - rlo;
    int gg = t / H;
    int j = t - gg * H;
    if (gg < 7) {
        float acc = 0.f;
        for (int r = rlo + gg; r < rhi; r += 7) acc += h[(long)r * H + j];
        partial[gg][j] = acc;
    }
    __syncthreads();
    if (t < H) {
        float s = 0.f;
#pragma unroll
        for (int k = 0; k < 7; ++k) s += partial[k][t];
        pooled[t] = s / fmaxf((float)cntg, 1.f);
    }
    __syncthreads();
    if (t < HOUT) {
        float acc = pb[t];
#pragma unroll
        for (int k = 0; k < H; ++k) acc += pooled[k] * pW[k * HOUT + t];
        float z = fmaxf(acc, 0.f) + log1pf(expf(-fabsf(acc)));  // softplus
        float pr = z * oW[t];
#pragma unroll
        for (int off = 32; off; off >>= 1) pr += __shfl_down(pr, off);
        if (t == 0) out[g] = pr + ob[0];
    }
}

static inline int grid_for(long n, int block = 256, long cap = 2048) {
    long b = (n + block - 1) / block;
    if (b > cap) b = cap;
    if (b < 1) b = 1;
    return (int)b;
}

extern "C" void kernel_launch(void* const* d_in, const int* in_sizes, int n_in,
                              void* d_out, int out_size, void* d_ws, size_t ws_size,
                              hipStream_t stream) {
    const float* x       = (const float*)d_in[0];
    const float* he      = (const float*)d_in[1];
    const int*   ni      = (const int*)d_in[2];
    const int*   ei      = (const int*)d_in[3];
    const int*   batch   = (const int*)d_in[4];
    const float* embed_W = (const float*)d_in[5];
    const float* embed_b = (const float*)d_in[6];
    const float* lin_W   = (const float*)d_in[7];   // [L,H,H]
    const float* att     = (const float*)d_in[8];   // [L,2H]
    const float* conv_b  = (const float*)d_in[9];   // [L,H]
    const float* proj_W  = (const float*)d_in[10];  // [H,HOUT]
    const float* proj_b  = (const float*)d_in[11];
    const float* out_W   = (const float*)d_in[12];  // [HOUT,1]
    const float* out_b   = (const float*)d_in[13];
    float* out = (float*)d_out;

    const int N    = in_sizes[0] / F_IN;  // 100000
    const int E    = in_sizes[1] / H;     // 50000
    const int NINC = in_sizes[2];         // 2000000
    const int G    = out_size;            // 256

    char* w = (char*)d_ws;
    auto alloc = [&](size_t bytes) {
        char* p = w;
        w += (bytes + 255) & ~(size_t)255;
        return p;
    };
    float* h     = (float*)alloc((size_t)N * H * 4);
    float* xl    = (float*)alloc((size_t)N * H * 4);
    float* e_out = (float*)alloc((size_t)E * H * 4);
    float* s_n   = (float*)alloc((size_t)N * 4);
    float* epack = (float*)alloc((size_t)E * 16);   // float4 {s_e, m, rec, -}
    float* w2    = (float*)alloc((size_t)H * 4);
    int*   ecnt  = (int*)alloc((size_t)E * 4);
    int*   eptr  = (int*)alloc((size_t)(E + 1) * 4);
    int*   ecur  = (int*)alloc((size_t)E * 4);
    int*   ncnt  = (int*)alloc((size_t)N * 4);
    int*   nptr  = (int*)alloc((size_t)(N + 1) * 4);
    int*   ncur  = (int*)alloc((size_t)N * 4);
    int*   enode = (int*)alloc((size_t)NINC * 4);
    int*   nedge = (int*)alloc((size_t)NINC * 4);

    const int BLK = 256;
    int gNH  = grid_for((long)N * H);
    int gNI  = grid_for(NINC);
    int gN   = grid_for(N);
    int gE   = grid_for(E);

    // ---- CSR build (once; same incidence structure for all layers) ----
    hipMemsetAsync(ncnt, 0, (size_t)N * 4, stream);
    hipMemsetAsync(ecnt, 0, (size_t)E * 4, stream);
    count_int_kernel<<<gNI, BLK, 0, stream>>>(ni, ei, ncnt, ecnt, NINC);
    scan_kernel<<<1, 1024, 0, stream>>>(ecnt, eptr, E);
    scan_kernel<<<1, 1024, 0, stream>>>(ncnt, nptr, N);
    hipMemcpyAsync(ecur, eptr, (size_t)E * 4, hipMemcpyDeviceToDevice, stream);
    hipMemcpyAsync(ncur, nptr, (size_t)N * 4, hipMemcpyDeviceToDevice, stream);
    csr_fill_kernel<<<gNI, BLK, 0, stream>>>(ni, ei, ecur, ncur, enode, nedge, NINC);

    // ---- embed ----
    embed_kernel<<<gNH, BLK, 0, stream>>>(x, embed_W, embed_b, h, N);

    // ---- layers ----
    int gEdge = (E + 3) / 4;   // 1 wave per edge
    int gNode = (N + 3) / 4;   // 1 wave per node
    for (int l = 0; l < NL; ++l) {
        const float* W  = lin_W + (size_t)l * H * H;
        const float* at = att + (size_t)l * 2 * H;
        const float* b  = conv_b + (size_t)l * H;

        lin_kernel<<<gNH, BLK, 0, stream>>>(h, W, xl, N);
        rowdot_kernel<<<gN, BLK, 0, stream>>>(xl, at, s_n, N, 1);
        wfold_kernel<<<1, 64, 0, stream>>>(W, at + H, w2);
        rowdot_kernel<<<gE, BLK, 0, stream>>>(he, w2, epack, E, 4);  // s_e -> epack.x

        edge_pass_kernel<<<gEdge, BLK, 0, stream>>>(eptr, enode, s_n, epack, xl, e_out, E);
        node_pass_kernel<<<gNode, BLK, 0, stream>>>(nptr, nedge, s_n, epack, e_out, b, h, N);
    }

    // ---- pooling + head ----
    pool_head_kernel<<<G, BLK, 0, stream>>>(h, batch, N, proj_W, proj_b, out_W, out_b, out);
}

// Round 5
// 1745.002 us; speedup vs baseline: 2.0842x; 1.0441x over previous
//
#include <hip/hip_runtime.h>
#include <hip/hip_bf16.h>
#include <limits.h>
#include <math.h>

#define F_IN 92
#define H 35
#define HOUT 64
#define NL 3
#define NEG_SLOPE 0.2f

// ------------------------------------------------------------------
// dense kernels
// ------------------------------------------------------------------

// h[n,j] = sum_k x[n,k] * W[k,j] + b[j]   (W: F_IN x H)
__global__ void embed_kernel(const float* __restrict__ x, const float* __restrict__ W,
                             const float* __restrict__ b, float* __restrict__ h, int N) {
    __shared__ float sW[F_IN * H];
    for (int t = threadIdx.x; t < F_IN * H; t += blockDim.x) sW[t] = W[t];
    __syncthreads();
    int total = N * H;
    int stride = gridDim.x * blockDim.x;
    for (int t = blockIdx.x * blockDim.x + threadIdx.x; t < total; t += stride) {
        int n = t / H, j = t - n * H;
        const float* xr = x + (long)n * F_IN;
        float acc = b[j];
#pragma unroll 4
        for (int k = 0; k < F_IN; ++k) acc += xr[k] * sW[k * H + j];
        h[t] = acc;
    }
}

// out[r,j] = sum_k in[r,k] * W[k,j]   (W: H x H, no bias)
__global__ void lin_kernel(const float* __restrict__ in, const float* __restrict__ W,
                           float* __restrict__ out, int R) {
    __shared__ float sW[H * H];
    for (int t = threadIdx.x; t < H * H; t += blockDim.x) sW[t] = W[t];
    __syncthreads();
    int total = R * H;
    int stride = gridDim.x * blockDim.x;
    for (int t = blockIdx.x * blockDim.x + threadIdx.x; t < total; t += stride) {
        int r = t / H, j = t - r * H;
        const float* ir = in + (long)r * H;
        float acc = 0.f;
#pragma unroll
        for (int k = 0; k < H; ++k) acc += ir[k] * sW[k * H + j];
        out[t] = acc;
    }
}

// s[r] = dot(in[r,:], vec[0:H])  -> s[r*stride_out]
__global__ void rowdot_kernel(const float* __restrict__ in, const float* __restrict__ vec,
                              float* __restrict__ s, int R, int stride_out) {
    __shared__ float sA[H];
    for (int t = threadIdx.x; t < H; t += blockDim.x) sA[t] = vec[t];
    __syncthreads();
    int stride = gridDim.x * blockDim.x;
    for (int r = blockIdx.x * blockDim.x + threadIdx.x; r < R; r += stride) {
        const float* xr = in + (long)r * H;
        float acc = 0.f;
#pragma unroll
        for (int k = 0; k < H; ++k) acc += xr[k] * sA[k];
        s[(long)r * stride_out] = acc;
    }
}

// w2[k] = sum_j W[k,j] * a[j]   (tiny: folds lin+att on hyperedge_attr)
__global__ void wfold_kernel(const float* __restrict__ W, const float* __restrict__ a,
                             float* __restrict__ w2) {
    int k = threadIdx.x;
    if (k < H) {
        float acc = 0.f;
#pragma unroll
        for (int j = 0; j < H; ++j) acc += W[k * H + j] * a[j];
        w2[k] = acc;
    }
}

// ------------------------------------------------------------------
// CSR build (indices identical across layers -> built once)
// ------------------------------------------------------------------

__global__ void count_int_kernel(const int* __restrict__ ni, const int* __restrict__ ei,
                                 int* __restrict__ ncnt, int* __restrict__ ecnt, int ninc) {
    int stride = gridDim.x * blockDim.x;
    for (int i = blockIdx.x * blockDim.x + threadIdx.x; i < ninc; i += stride) {
        int v = __builtin_nontemporal_load(ni + i);   // nt: don't evict dirty L2 lines
        int e = __builtin_nontemporal_load(ei + i);
        atomicAdd(&ncnt[v], 1);
        atomicAdd(&ecnt[e], 1);
    }
}

// dual exclusive scan: block 0 -> (cnt0, ptr0, cur0, n0), block 1 -> (cnt1, ptr1, cur1, n1)
// also writes the cursor copy (removes two d2d memcpy launches)
__global__ void scan2_kernel(const int* __restrict__ cnt0, int* __restrict__ ptr0,
                             int* __restrict__ cur0, int n0,
                             const int* __restrict__ cnt1, int* __restrict__ ptr1,
                             int* __restrict__ cur1, int n1) {
    const int* cnt = blockIdx.x ? cnt1 : cnt0;
    int* ptr = blockIdx.x ? ptr1 : ptr0;
    int* cur = blockIdx.x ? cur1 : cur0;
    int n = blockIdx.x ? n1 : n0;
    __shared__ int part[1024];
    int t = threadIdx.x;
    int chunk = (n + 1023) / 1024;
    int lo = t * chunk;
    int hi = lo + chunk; if (hi > n) hi = n; if (lo > n) lo = n;
    int s = 0;
    for (int i = lo; i < hi; ++i) s += cnt[i];
    part[t] = s;
    __syncthreads();
    for (int off = 1; off < 1024; off <<= 1) {
        int v = (t >= off) ? part[t - off] : 0;
        __syncthreads();
        part[t] += v;
        __syncthreads();
    }
    int base = (t == 0) ? 0 : part[t - 1];
    for (int i = lo; i < hi; ++i) { ptr[i] = base; cur[i] = base; base += cnt[i]; }
    if (t == 1023) ptr[n] = part[1023];
}

// counting-sort fill: edge-CSR stores node ids, node-CSR stores edge ids
__global__ void csr_fill_kernel(const int* __restrict__ ni, const int* __restrict__ ei,
                                int* __restrict__ ecur, int* __restrict__ ncur,
                                int* __restrict__ enode, int* __restrict__ nedge, int ninc) {
    int stride = gridDim.x * blockDim.x;
    for (int i = blockIdx.x * blockDim.x + threadIdx.x; i < ninc; i += stride) {
        int v = __builtin_nontemporal_load(ni + i);   // nt: keep L2 for dirty scatter lines
        int e = __builtin_nontemporal_load(ei + i);
        int p = atomicAdd(&ecur[e], 1); enode[p] = v;
        int q = atomicAdd(&ncur[v], 1); nedge[q] = e;
    }
}

// ------------------------------------------------------------------
// fused sparse passes (atomic-free, 1 wave per segment, single-load,
// LDS-broadcast inner gather instead of ds_bpermute shuffles)
// ------------------------------------------------------------------

__device__ __forceinline__ float wave_max(float m) {
#pragma unroll
    for (int off = 32; off; off >>= 1) m = fmaxf(m, __shfl_xor(m, off));
    return m;
}
__device__ __forceinline__ float wave_sum(float s) {
#pragma unroll
    for (int off = 32; off; off >>= 1) s += __shfl_xor(s, off);
    return s;
}

// per edge e: softmax over incident nodes + weighted accumulation into e_out[e,:]
// epack[e] = {s_e, m, 1/(sum+eps), -}; reads epack.x, writes .y/.z
__global__ void edge_pass_kernel(const int* __restrict__ eptr, const int* __restrict__ enode,
                                 const float* __restrict__ s_n, float* __restrict__ epack,
                                 const float* __restrict__ xl,
                                 float* __restrict__ e_out, int E) {
    __shared__ float shA[4][64];
    __shared__ int   shV[4][64];
    int lane = threadIdx.x & 63;
    int ws = threadIdx.x >> 6;
    int wid = (blockIdx.x * blockDim.x + threadIdx.x) >> 6;
    int nw = (gridDim.x * blockDim.x) >> 6;
    for (int e = wid; e < E; e += nw) {
        int lo = eptr[e], hi = eptr[e + 1];
        int deg = hi - lo;
        float se = epack[4 * (long)e];
        float binv = deg > 0 ? 1.f / (float)deg : 0.f;
        float acc = 0.f;
        float mm, rec;
        if (deg <= 64) {
            // single lane-parallel load of the whole segment
            int v = 0; float sc = -INFINITY;
            if (lane < deg) {
                v = enode[lo + lane];
                sc = s_n[v] + se;
                sc = sc >= 0.f ? sc : NEG_SLOPE * sc;
            }
            float m = wave_max(sc);
            mm = (m == -INFINITY) ? 0.f : m;
            float ex = (lane < deg) ? expf(sc - mm) : 0.f;
            float s = wave_sum(ex);
            rec = 1.f / (s + 1e-16f);
            // stage (alpha, v) in LDS once; inner loop = broadcast reads
            shA[ws][lane] = ex * rec * binv;
            shV[ws][lane] = v;
#pragma unroll 4
            for (int k = 0; k < deg; ++k) {
                float ak = shA[ws][k];
                int vk = shV[ws][k];
                if (lane < H) acc += ak * xl[(long)vk * H + lane];
            }
        } else {
            float m = -INFINITY;
            for (int k = lo + lane; k < hi; k += 64) {
                float sc = s_n[enode[k]] + se;
                sc = sc >= 0.f ? sc : NEG_SLOPE * sc;
                m = fmaxf(m, sc);
            }
            m = wave_max(m);
            mm = (m == -INFINITY) ? 0.f : m;
            float s = 0.f;
            for (int k = lo + lane; k < hi; k += 64) {
                float sc = s_n[enode[k]] + se;
                sc = sc >= 0.f ? sc : NEG_SLOPE * sc;
                s += expf(sc - mm);
            }
            s = wave_sum(s);
            rec = 1.f / (s + 1e-16f);
            float cb = rec * binv;
            for (int base = lo; base < hi; base += 64) {
                int v = 0; float a = 0.f;
                if (base + lane < hi) {
                    v = enode[base + lane];
                    float sc = s_n[v] + se;
                    sc = sc >= 0.f ? sc : NEG_SLOPE * sc;
                    a = expf(sc - mm) * cb;
                }
                shA[ws][lane] = a;
                shV[ws][lane] = v;
                int cn = hi - base; if (cn > 64) cn = 64;
#pragma unroll 4
                for (int k = 0; k < cn; ++k) {
                    float ak = shA[ws][k];
                    int vk = shV[ws][k];
                    if (lane < H) acc += ak * xl[(long)vk * H + lane];
                }
            }
        }
        if (lane < H) e_out[(long)e * H + lane] = acc;
        if (lane == 0) { epack[4 * (long)e + 1] = mm; epack[4 * (long)e + 2] = rec; }
    }
}

// per node v: h[v,j] = Dinv * sum_i alpha_i * e_out[e_i, j] + bias[j]
__global__ void node_pass_kernel(const int* __restrict__ nptr, const int* __restrict__ nedge,
                                 const float* __restrict__ s_n, const float* __restrict__ epack,
                                 const float* __restrict__ e_out, const float* __restrict__ bias,
                                 float* __restrict__ hout, int N) {
    __shared__ float shA[4][64];
    __shared__ int   shE[4][64];
    int lane = threadIdx.x & 63;
    int ws = threadIdx.x >> 6;
    int wid = (blockIdx.x * blockDim.x + threadIdx.x) >> 6;
    int nw = (gridDim.x * blockDim.x) >> 6;
    for (int v = wid; v < N; v += nw) {
        int lo = nptr[v], hi = nptr[v + 1];
        int deg = hi - lo;
        float dinv = deg > 0 ? 1.f / (float)deg : 0.f;
        float sn = s_n[v];
        float acc = 0.f;
        if (deg <= 64) {
            int e = 0; float a = 0.f;
            if (lane < deg) {
                e = nedge[lo + lane];
                float4 p = ((const float4*)epack)[e];   // {s_e, m, rec, -} one 16B gather
                float sc = sn + p.x;
                sc = sc >= 0.f ? sc : NEG_SLOPE * sc;
                a = expf(sc - p.y) * p.z;
            }
            shA[ws][lane] = a;
            shE[ws][lane] = e;
#pragma unroll 4
            for (int k = 0; k < deg; ++k) {
                float ak = shA[ws][k];
                int ek = shE[ws][k];
                if (lane < H) acc += ak * e_out[(long)ek * H + lane];
            }
        } else {
            for (int base = lo; base < hi; base += 64) {
                int e = 0; float a = 0.f;
                if (base + lane < hi) {
                    e = nedge[base + lane];
                    float4 p = ((const float4*)epack)[e];
                    float sc = sn + p.x;
                    sc = sc >= 0.f ? sc : NEG_SLOPE * sc;
                    a = expf(sc - p.y) * p.z;
                }
                shA[ws][lane] = a;
                shE[ws][lane] = e;
                int cn = hi - base; if (cn > 64) cn = 64;
#pragma unroll 4
                for (int k = 0; k < cn; ++k) {
                    float ak = shA[ws][k];
                    int ek = shE[ws][k];
                    if (lane < H) acc += ak * e_out[(long)ek * H + lane];
                }
            }
        }
        if (lane < H) hout[(long)v * H + lane] = dinv * acc + bias[lane];
    }
}

// ------------------------------------------------------------------
// fused pooling (batch sorted -> binary search) + MLP head
// ------------------------------------------------------------------
__global__ void pool_head_kernel(const float* __restrict__ h, const int* __restrict__ batch,
                                 int N, const float* __restrict__ pW, const float* __restrict__ pb,
                                 const float* __restrict__ oW, const float* __restrict__ ob,
                                 float* __restrict__ out) {
    int g = blockIdx.x;
    int t = threadIdx.x;
    __shared__ int bounds[2];
    __shared__ float partial[7][H];
    __shared__ float pooled[H];
    if (t == 0) {
        int lo = 0, hi = N;
        while (lo < hi) { int mid = (lo + hi) >> 1; if (batch[mid] < g) lo = mid + 1; else hi = mid; }
        bounds[0] = lo;
        int lo2 = lo, hi2 = N;
        while (lo2 < hi2) { int mid = (lo2 + hi2) >> 1; if (batch[mid] < g + 1) lo2 = mid + 1; else hi2 = mid; }
        bounds[1] = lo2;
    }
    __syncthreads();
    int rlo = bounds[0], rhi = bounds[1];
    int cntg = rhi - rlo;
    int gg = t / H;
    int j = t - gg * H;
    if (gg < 7) {
        float acc = 0.f;
        for (int r = rlo + gg; r < rhi; r += 7) acc += h[(long)r * H + j];
        partial[gg][j] = acc;
    }
    __syncthreads();
    if (t < H) {
        float s = 0.f;
#pragma unroll
        for (int k = 0; k < 7; ++k) s += partial[k][t];
        pooled[t] = s / fmaxf((float)cntg, 1.f);
    }
    __syncthreads();
    if (t < HOUT) {
        float acc = pb[t];
#pragma unroll
        for (int k = 0; k < H; ++k) acc += pooled[k] * pW[k * HOUT + t];
        float z = fmaxf(acc, 0.f) + log1pf(expf(-fabsf(acc)));  // softplus
        float pr = z * oW[t];
#pragma unroll
        for (int off = 32; off; off >>= 1) pr += __shfl_down(pr, off);
        if (t == 0) out[g] = pr + ob[0];
    }
}

static inline int grid_for(long n, int block = 256, long cap = 2048) {
    long b = (n + block - 1) / block;
    if (b > cap) b = cap;
    if (b < 1) b = 1;
    return (int)b;
}

extern "C" void kernel_launch(void* const* d_in, const int* in_sizes, int n_in,
                              void* d_out, int out_size, void* d_ws, size_t ws_size,
                              hipStream_t stream) {
    const float* x       = (const float*)d_in[0];
    const float* he      = (const float*)d_in[1];
    const int*   ni      = (const int*)d_in[2];
    const int*   ei      = (const int*)d_in[3];
    const int*   batch   = (const int*)d_in[4];
    const float* embed_W = (const float*)d_in[5];
    const float* embed_b = (const float*)d_in[6];
    const float* lin_W   = (const float*)d_in[7];   // [L,H,H]
    const float* att     = (const float*)d_in[8];   // [L,2H]
    const float* conv_b  = (const float*)d_in[9];   // [L,H]
    const float* proj_W  = (const float*)d_in[10];  // [H,HOUT]
    const float* proj_b  = (const float*)d_in[11];
    const float* out_W   = (const float*)d_in[12];  // [HOUT,1]
    const float* out_b   = (const float*)d_in[13];
    float* out = (float*)d_out;

    const int N    = in_sizes[0] / F_IN;  // 100000
    const int E    = in_sizes[1] / H;     // 50000
    const int NINC = in_sizes[2];         // 2000000
    const int G    = out_size;            // 256

    char* w = (char*)d_ws;
    auto alloc = [&](size_t bytes) {
        char* p = w;
        w += (bytes + 255) & ~(size_t)255;
        return p;
    };
    float* h     = (float*)alloc((size_t)N * H * 4);
    float* xl    = (float*)alloc((size_t)N * H * 4);
    float* e_out = (float*)alloc((size_t)E * H * 4);
    float* s_n   = (float*)alloc((size_t)N * 4);
    float* epack = (float*)alloc((size_t)E * 16);   // float4 {s_e, m, rec, -}
    float* w2    = (float*)alloc((size_t)H * 4);
    int*   ecnt  = (int*)alloc((size_t)E * 4);
    int*   eptr  = (int*)alloc((size_t)(E + 1) * 4);
    int*   ecur  = (int*)alloc((size_t)E * 4);
    int*   ncnt  = (int*)alloc((size_t)N * 4);
    int*   nptr  = (int*)alloc((size_t)(N + 1) * 4);
    int*   ncur  = (int*)alloc((size_t)N * 4);
    int*   enode = (int*)alloc((size_t)NINC * 4);
    int*   nedge = (int*)alloc((size_t)NINC * 4);

    const int BLK = 256;
    int gNH  = grid_for((long)N * H);
    int gNI  = grid_for(NINC);
    int gN   = grid_for(N);
    int gE   = grid_for(E);

    // ---- CSR build (once; same incidence structure for all layers) ----
    hipMemsetAsync(ncnt, 0, (size_t)N * 4, stream);
    hipMemsetAsync(ecnt, 0, (size_t)E * 4, stream);
    count_int_kernel<<<gNI, BLK, 0, stream>>>(ni, ei, ncnt, ecnt, NINC);
    scan2_kernel<<<2, 1024, 0, stream>>>(ecnt, eptr, ecur, E, ncnt, nptr, ncur, N);
    csr_fill_kernel<<<gNI, BLK, 0, stream>>>(ni, ei, ecur, ncur, enode, nedge, NINC);

    // ---- embed ----
    embed_kernel<<<gNH, BLK, 0, stream>>>(x, embed_W, embed_b, h, N);

    // ---- layers ----
    int gEdge = (E + 3) / 4;   // 1 wave per edge
    int gNode = (N + 3) / 4;   // 1 wave per node
    for (int l = 0; l < NL; ++l) {
        const float* W  = lin_W + (size_t)l * H * H;
        const float* at = att + (size_t)l * 2 * H;
        const float* b  = conv_b + (size_t)l * H;

        lin_kernel<<<gNH, BLK, 0, stream>>>(h, W, xl, N);
        rowdot_kernel<<<gN, BLK, 0, stream>>>(xl, at, s_n, N, 1);
        wfold_kernel<<<1, 64, 0, stream>>>(W, at + H, w2);
        rowdot_kernel<<<gE, BLK, 0, stream>>>(he, w2, epack, E, 4);  // s_e -> epack.x

        edge_pass_kernel<<<gEdge, BLK, 0, stream>>>(eptr, enode, s_n, epack, xl, e_out, E);
        node_pass_kernel<<<gNode, BLK, 0, stream>>>(nptr, nedge, s_n, epack, e_out, b, h, N);
    }

    // ---- pooling + head ----
    pool_head_kernel<<<G, BLK, 0, stream>>>(h, batch, N, proj_W, proj_b, out_W, out_b, out);
}

// Round 8
// 1587.471 us; speedup vs baseline: 2.2910x; 1.0992x over previous
//
#include <hip/hip_runtime.h>
#include <hip/hip_bf16.h>
#include <limits.h>
#include <math.h>

#define F_IN 92
#define H 35
#define HOUT 64
#define NL 3
#define NEG_SLOPE 0.2f
#define NSLICE 8

typedef int iv4 __attribute__((ext_vector_type(4)));   // clang vector: valid for nontemporal builtins

// ------------------------------------------------------------------
// dense kernels
// ------------------------------------------------------------------

// h[n,j] = sum_k x[n,k] * W[k,j] + b[j]   (W: F_IN x H)
__global__ void embed_kernel(const float* __restrict__ x, const float* __restrict__ W,
                             const float* __restrict__ b, float* __restrict__ h, int N) {
    __shared__ float sW[F_IN * H];
    for (int t = threadIdx.x; t < F_IN * H; t += blockDim.x) sW[t] = W[t];
    __syncthreads();
    int total = N * H;
    int stride = gridDim.x * blockDim.x;
    for (int t = blockIdx.x * blockDim.x + threadIdx.x; t < total; t += stride) {
        int n = t / H, j = t - n * H;
        const float* xr = x + (long)n * F_IN;
        float acc = b[j];
#pragma unroll 4
        for (int k = 0; k < F_IN; ++k) acc += xr[k] * sW[k * H + j];
        h[t] = acc;
    }
}

// out[r,j] = sum_k in[r,k] * W[k,j]   (W: H x H, no bias)
__global__ void lin_kernel(const float* __restrict__ in, const float* __restrict__ W,
                           float* __restrict__ out, int R) {
    __shared__ float sW[H * H];
    for (int t = threadIdx.x; t < H * H; t += blockDim.x) sW[t] = W[t];
    __syncthreads();
    int total = R * H;
    int stride = gridDim.x * blockDim.x;
    for (int t = blockIdx.x * blockDim.x + threadIdx.x; t < total; t += stride) {
        int r = t / H, j = t - r * H;
        const float* ir = in + (long)r * H;
        float acc = 0.f;
#pragma unroll
        for (int k = 0; k < H; ++k) acc += ir[k] * sW[k * H + j];
        out[t] = acc;
    }
}

// s[r] = dot(in[r,:], vec[0:H])  -> s[r*stride_out]
__global__ void rowdot_kernel(const float* __restrict__ in, const float* __restrict__ vec,
                              float* __restrict__ s, int R, int stride_out) {
    __shared__ float sA[H];
    for (int t = threadIdx.x; t < H; t += blockDim.x) sA[t] = vec[t];
    __syncthreads();
    int stride = gridDim.x * blockDim.x;
    for (int r = blockIdx.x * blockDim.x + threadIdx.x; r < R; r += stride) {
        const float* xr = in + (long)r * H;
        float acc = 0.f;
#pragma unroll
        for (int k = 0; k < H; ++k) acc += xr[k] * sA[k];
        s[(long)r * stride_out] = acc;
    }
}

// w2[k] = sum_j W[k,j] * a[j]   (tiny: folds lin+att on hyperedge_attr)
__global__ void wfold_kernel(const float* __restrict__ W, const float* __restrict__ a,
                             float* __restrict__ w2) {
    int k = threadIdx.x;
    if (k < H) {
        float acc = 0.f;
#pragma unroll
        for (int j = 0; j < H; ++j) acc += W[k * H + j] * a[j];
        w2[k] = acc;
    }
}

// ------------------------------------------------------------------
// CSR build — destination-sliced so each slice's dirty lines live in
// one XCD's L2 (blockIdx&7 -> XCD under round-robin dispatch; perf
// heuristic only, correctness independent of mapping)
// ------------------------------------------------------------------

__global__ void count_sliced_kernel(const int* __restrict__ ni, const int* __restrict__ ei,
                                    int* __restrict__ ncnt, int* __restrict__ ecnt,
                                    int ninc, int wN, int wE) {
    int s = blockIdx.x & (NSLICE - 1);
    int loN = s * wN, hiN = loN + wN;
    int loE = s * wE, hiE = loE + wE;
    int nblk = gridDim.x >> 3;
    int bid = blockIdx.x >> 3;
    int nvec = ninc >> 2;
    int stride = nblk * blockDim.x;
    for (int q = bid * blockDim.x + threadIdx.x; q < nvec; q += stride) {
        iv4 v4 = __builtin_nontemporal_load((const iv4*)ni + q);
        iv4 e4 = __builtin_nontemporal_load((const iv4*)ei + q);
#pragma unroll
        for (int u = 0; u < 4; ++u) {
            int e = e4[u], v = v4[u];
            if (e >= loE && e < hiE) atomicAdd(&ecnt[e], 1);
            if (v >= loN && v < hiN) atomicAdd(&ncnt[v], 1);
        }
    }
    // scalar tail (ninc % 4), covered once per slice by its first block
    if (bid == 0) {
        for (int i = (nvec << 2) + threadIdx.x; i < ninc; i += blockDim.x) {
            int v = ni[i], e = ei[i];
            if (e >= loE && e < hiE) atomicAdd(&ecnt[e], 1);
            if (v >= loN && v < hiN) atomicAdd(&ncnt[v], 1);
        }
    }
}

// dual exclusive scan: block 0 -> (cnt0, ptr0, cur0, n0), block 1 -> (cnt1, ptr1, cur1, n1)
__global__ void scan2_kernel(const int* __restrict__ cnt0, int* __restrict__ ptr0,
                             int* __restrict__ cur0, int n0,
                             const int* __restrict__ cnt1, int* __restrict__ ptr1,
                             int* __restrict__ cur1, int n1) {
    const int* cnt = blockIdx.x ? cnt1 : cnt0;
    int* ptr = blockIdx.x ? ptr1 : ptr0;
    int* cur = blockIdx.x ? cur1 : cur0;
    int n = blockIdx.x ? n1 : n0;
    __shared__ int part[1024];
    int t = threadIdx.x;
    int chunk = (n + 1023) / 1024;
    int lo = t * chunk;
    int hi = lo + chunk; if (hi > n) hi = n; if (lo > n) lo = n;
    int s = 0;
    for (int i = lo; i < hi; ++i) s += cnt[i];
    part[t] = s;
    __syncthreads();
    for (int off = 1; off < 1024; off <<= 1) {
        int v = (t >= off) ? part[t - off] : 0;
        __syncthreads();
        part[t] += v;
        __syncthreads();
    }
    int base = (t == 0) ? 0 : part[t - 1];
    for (int i = lo; i < hi; ++i) { ptr[i] = base; cur[i] = base; base += cnt[i]; }
    if (t == 1023) ptr[n] = part[1023];
}

// sliced counting-sort fill: slice s handles scatter targets in its id-range only
__global__ void csr_fill_sliced_kernel(const int* __restrict__ ni, const int* __restrict__ ei,
                                       int* __restrict__ ecur, int* __restrict__ ncur,
                                       int* __restrict__ enode, int* __restrict__ nedge,
                                       int ninc, int wN, int wE) {
    int s = blockIdx.x & (NSLICE - 1);
    int loN = s * wN, hiN = loN + wN;
    int loE = s * wE, hiE = loE + wE;
    int nblk = gridDim.x >> 3;
    int bid = blockIdx.x >> 3;
    int nvec = ninc >> 2;
    int stride = nblk * blockDim.x;
    for (int q = bid * blockDim.x + threadIdx.x; q < nvec; q += stride) {
        iv4 v4 = __builtin_nontemporal_load((const iv4*)ni + q);
        iv4 e4 = __builtin_nontemporal_load((const iv4*)ei + q);
#pragma unroll
        for (int u = 0; u < 4; ++u) {
            int e = e4[u], v = v4[u];
            if (e >= loE && e < hiE) {
                int p = atomicAdd(&ecur[e], 1);
                enode[p] = v;
            }
            if (v >= loN && v < hiN) {
                int p = atomicAdd(&ncur[v], 1);
                nedge[p] = e;
            }
        }
    }
    if (bid == 0) {
        for (int i = (nvec << 2) + threadIdx.x; i < ninc; i += blockDim.x) {
            int v = ni[i], e = ei[i];
            if (e >= loE && e < hiE) { int p = atomicAdd(&ecur[e], 1); enode[p] = v; }
            if (v >= loN && v < hiN) { int p = atomicAdd(&ncur[v], 1); nedge[p] = e; }
        }
    }
}

// ------------------------------------------------------------------
// fused sparse passes (atomic-free, 1 wave per segment, single-load,
// LDS-broadcast inner gather)
// ------------------------------------------------------------------

__device__ __forceinline__ float wave_max(float m) {
#pragma unroll
    for (int off = 32; off; off >>= 1) m = fmaxf(m, __shfl_xor(m, off));
    return m;
}
__device__ __forceinline__ float wave_sum(float s) {
#pragma unroll
    for (int off = 32; off; off >>= 1) s += __shfl_xor(s, off);
    return s;
}

// per edge e: softmax over incident nodes + weighted accumulation into e_out[e,:]
// epack[e] = {s_e, m, 1/(sum+eps), -}; reads epack.x, writes .y/.z
__global__ void edge_pass_kernel(const int* __restrict__ eptr, const int* __restrict__ enode,
                                 const float* __restrict__ s_n, float* __restrict__ epack,
                                 const float* __restrict__ xl,
                                 float* __restrict__ e_out, int E) {
    __shared__ float shA[4][64];
    __shared__ int   shV[4][64];
    int lane = threadIdx.x & 63;
    int ws = threadIdx.x >> 6;
    int wid = (blockIdx.x * blockDim.x + threadIdx.x) >> 6;
    int nw = (gridDim.x * blockDim.x) >> 6;
    for (int e = wid; e < E; e += nw) {
        int lo = eptr[e], hi = eptr[e + 1];
        int deg = hi - lo;
        float se = epack[4 * (long)e];
        float binv = deg > 0 ? 1.f / (float)deg : 0.f;
        float acc = 0.f;
        float mm, rec;
        if (deg <= 64) {
            int v = 0; float sc = -INFINITY;
            if (lane < deg) {
                v = enode[lo + lane];
                sc = s_n[v] + se;
                sc = sc >= 0.f ? sc : NEG_SLOPE * sc;
            }
            float m = wave_max(sc);
            mm = (m == -INFINITY) ? 0.f : m;
            float ex = (lane < deg) ? expf(sc - mm) : 0.f;
            float s = wave_sum(ex);
            rec = 1.f / (s + 1e-16f);
            shA[ws][lane] = ex * rec * binv;
            shV[ws][lane] = v;
#pragma unroll 4
            for (int k = 0; k < deg; ++k) {
                float ak = shA[ws][k];
                int vk = shV[ws][k];
                if (lane < H) acc += ak * xl[(long)vk * H + lane];
            }
        } else {
            float m = -INFINITY;
            for (int k = lo + lane; k < hi; k += 64) {
                float sc = s_n[enode[k]] + se;
                sc = sc >= 0.f ? sc : NEG_SLOPE * sc;
                m = fmaxf(m, sc);
            }
            m = wave_max(m);
            mm = (m == -INFINITY) ? 0.f : m;
            float s = 0.f;
            for (int k = lo + lane; k < hi; k += 64) {
                float sc = s_n[enode[k]] + se;
                sc = sc >= 0.f ? sc : NEG_SLOPE * sc;
                s += expf(sc - mm);
            }
            s = wave_sum(s);
            rec = 1.f / (s + 1e-16f);
            float cb = rec * binv;
            for (int base = lo; base < hi; base += 64) {
                int v = 0; float a = 0.f;
                if (base + lane < hi) {
                    v = enode[base + lane];
                    float sc = s_n[v] + se;
                    sc = sc >= 0.f ? sc : NEG_SLOPE * sc;
                    a = expf(sc - mm) * cb;
                }
                shA[ws][lane] = a;
                shV[ws][lane] = v;
                int cn = hi - base; if (cn > 64) cn = 64;
#pragma unroll 4
                for (int k = 0; k < cn; ++k) {
                    float ak = shA[ws][k];
                    int vk = shV[ws][k];
                    if (lane < H) acc += ak * xl[(long)vk * H + lane];
                }
            }
        }
        if (lane < H) e_out[(long)e * H + lane] = acc;
        if (lane == 0) { epack[4 * (long)e + 1] = mm; epack[4 * (long)e + 2] = rec; }
    }
}

// per node v: h[v,j] = Dinv * sum_i alpha_i * e_out[e_i, j] + bias[j]
__global__ void node_pass_kernel(const int* __restrict__ nptr, const int* __restrict__ nedge,
                                 const float* __restrict__ s_n, const float* __restrict__ epack,
                                 const float* __restrict__ e_out, const float* __restrict__ bias,
                                 float* __restrict__ hout, int N) {
    __shared__ float shA[4][64];
    __shared__ int   shE[4][64];
    int lane = threadIdx.x & 63;
    int ws = threadIdx.x >> 6;
    int wid = (blockIdx.x * blockDim.x + threadIdx.x) >> 6;
    int nw = (gridDim.x * blockDim.x) >> 6;
    for (int v = wid; v < N; v += nw) {
        int lo = nptr[v], hi = nptr[v + 1];
        int deg = hi - lo;
        float dinv = deg > 0 ? 1.f / (float)deg : 0.f;
        float sn = s_n[v];
        float acc = 0.f;
        if (deg <= 64) {
            int e = 0; float a = 0.f;
            if (lane < deg) {
                e = nedge[lo + lane];
                float4 p = ((const float4*)epack)[e];   // {s_e, m, rec, -} one 16B gather
                float sc = sn + p.x;
                sc = sc >= 0.f ? sc : NEG_SLOPE * sc;
                a = expf(sc - p.y) * p.z;
            }
            shA[ws][lane] = a;
            shE[ws][lane] = e;
#pragma unroll 4
            for (int k = 0; k < deg; ++k) {
                float ak = shA[ws][k];
                int ek = shE[ws][k];
                if (lane < H) acc += ak * e_out[(long)ek * H + lane];
            }
        } else {
            for (int base = lo; base < hi; base += 64) {
                int e = 0; float a = 0.f;
                if (base + lane < hi) {
                    e = nedge[base + lane];
                    float4 p = ((const float4*)epack)[e];
                    float sc = sn + p.x;
                    sc = sc >= 0.f ? sc : NEG_SLOPE * sc;
                    a = expf(sc - p.y) * p.z;
                }
                shA[ws][lane] = a;
                shE[ws][lane] = e;
                int cn = hi - base; if (cn > 64) cn = 64;
#pragma unroll 4
                for (int k = 0; k < cn; ++k) {
                    float ak = shA[ws][k];
                    int ek = shE[ws][k];
                    if (lane < H) acc += ak * e_out[(long)ek * H + lane];
                }
            }
        }
        if (lane < H) hout[(long)v * H + lane] = dinv * acc + bias[lane];
    }
}

// ------------------------------------------------------------------
// fused pooling (batch sorted -> binary search) + MLP head
// ------------------------------------------------------------------
__global__ void pool_head_kernel(const float* __restrict__ h, const int* __restrict__ batch,
                                 int N, const float* __restrict__ pW, const float* __restrict__ pb,
                                 const float* __restrict__ oW, const float* __restrict__ ob,
                                 float* __restrict__ out) {
    int g = blockIdx.x;
    int t = threadIdx.x;
    __shared__ int bounds[2];
    __shared__ float partial[7][H];
    __shared__ float pooled[H];
    if (t == 0) {
        int lo = 0, hi = N;
        while (lo < hi) { int mid = (lo + hi) >> 1; if (batch[mid] < g) lo = mid + 1; else hi = mid; }
        bounds[0] = lo;
        int lo2 = lo, hi2 = N;
        while (lo2 < hi2) { int mid = (lo2 + hi2) >> 1; if (batch[mid] < g + 1) lo2 = mid + 1; else hi2 = mid; }
        bounds[1] = lo2;
    }
    __syncthreads();
    int rlo = bounds[0], rhi = bounds[1];
    int cntg = rhi - rlo;
    int gg = t / H;
    int j = t - gg * H;
    if (gg < 7) {
        float acc = 0.f;
        for (int r = rlo + gg; r < rhi; r += 7) acc += h[(long)r * H + j];
        partial[gg][j] = acc;
    }
    __syncthreads();
    if (t < H) {
        float s = 0.f;
#pragma unroll
        for (int k = 0; k < 7; ++k) s += partial[k][t];
        pooled[t] = s / fmaxf((float)cntg, 1.f);
    }
    __syncthreads();
    if (t < HOUT) {
        float acc = pb[t];
#pragma unroll
        for (int k = 0; k < H; ++k) acc += pooled[k] * pW[k * HOUT + t];
        float z = fmaxf(acc, 0.f) + log1pf(expf(-fabsf(acc)));  // softplus
        float pr = z * oW[t];
#pragma unroll
        for (int off = 32; off; off >>= 1) pr += __shfl_down(pr, off);
        if (t == 0) out[g] = pr + ob[0];
    }
}

static inline int grid_for(long n, int block = 256, long cap = 2048) {
    long b = (n + block - 1) / block;
    if (b > cap) b = cap;
    if (b < 1) b = 1;
    return (int)b;
}

extern "C" void kernel_launch(void* const* d_in, const int* in_sizes, int n_in,
                              void* d_out, int out_size, void* d_ws, size_t ws_size,
                              hipStream_t stream) {
    const float* x       = (const float*)d_in[0];
    const float* he      = (const float*)d_in[1];
    const int*   ni      = (const int*)d_in[2];
    const int*   ei      = (const int*)d_in[3];
    const int*   batch   = (const int*)d_in[4];
    const float* embed_W = (const float*)d_in[5];
    const float* embed_b = (const float*)d_in[6];
    const float* lin_W   = (const float*)d_in[7];   // [L,H,H]
    const float* att     = (const float*)d_in[8];   // [L,2H]
    const float* conv_b  = (const float*)d_in[9];   // [L,H]
    const float* proj_W  = (const float*)d_in[10];  // [H,HOUT]
    const float* proj_b  = (const float*)d_in[11];
    const float* out_W   = (const float*)d_in[12];  // [HOUT,1]
    const float* out_b   = (const float*)d_in[13];
    float* out = (float*)d_out;

    const int N    = in_sizes[0] / F_IN;  // 100000
    const int E    = in_sizes[1] / H;     // 50000
    const int NINC = in_sizes[2];         // 2000000
    const int G    = out_size;            // 256

    char* w = (char*)d_ws;
    auto alloc = [&](size_t bytes) {
        char* p = w;
        w += (bytes + 255) & ~(size_t)255;
        return p;
    };
    float* h     = (float*)alloc((size_t)N * H * 4);
    float* xl    = (float*)alloc((size_t)N * H * 4);
    float* e_out = (float*)alloc((size_t)E * H * 4);
    float* s_n   = (float*)alloc((size_t)N * 4);
    float* epack = (float*)alloc((size_t)E * 16);   // float4 {s_e, m, rec, -}
    float* w2    = (float*)alloc((size_t)H * 4);
    int*   ecnt  = (int*)alloc((size_t)E * 4);
    int*   eptr  = (int*)alloc((size_t)(E + 1) * 4);
    int*   ecur  = (int*)alloc((size_t)E * 4);
    int*   ncnt  = (int*)alloc((size_t)N * 4);
    int*   nptr  = (int*)alloc((size_t)(N + 1) * 4);
    int*   ncur  = (int*)alloc((size_t)N * 4);
    int*   enode = (int*)alloc((size_t)NINC * 4);
    int*   nedge = (int*)alloc((size_t)NINC * 4);

    const int BLK = 256;
    int gNH  = grid_for((long)N * H);
    int gN   = grid_for(N);
    int gE   = grid_for(E);
    int wN   = (N + NSLICE - 1) / NSLICE;   // 12500
    int wE   = (E + NSLICE - 1) / NSLICE;   // 6250

    // ---- CSR build (once; same incidence structure for all layers) ----
    (void)hipMemsetAsync(ncnt, 0, (size_t)N * 4, stream);
    (void)hipMemsetAsync(ecnt, 0, (size_t)E * 4, stream);
    count_sliced_kernel<<<2048, BLK, 0, stream>>>(ni, ei, ncnt, ecnt, NINC, wN, wE);
    scan2_kernel<<<2, 1024, 0, stream>>>(ecnt, eptr, ecur, E, ncnt, nptr, ncur, N);
    csr_fill_sliced_kernel<<<2048, BLK, 0, stream>>>(ni, ei, ecur, ncur, enode, nedge,
                                                     NINC, wN, wE);

    // ---- embed ----
    embed_kernel<<<gNH, BLK, 0, stream>>>(x, embed_W, embed_b, h, N);

    // ---- layers ----
    int gEdge = (E + 3) / 4;   // 1 wave per edge
    int gNode = (N + 3) / 4;   // 1 wave per node
    for (int l = 0; l < NL; ++l) {
        const float* W  = lin_W + (size_t)l * H * H;
        const float* at = att + (size_t)l * 2 * H;
        const float* b  = conv_b + (size_t)l * H;

        lin_kernel<<<gNH, BLK, 0, stream>>>(h, W, xl, N);
        rowdot_kernel<<<gN, BLK, 0, stream>>>(xl, at, s_n, N, 1);
        wfold_kernel<<<1, 64, 0, stream>>>(W, at + H, w2);
        rowdot_kernel<<<gE, BLK, 0, stream>>>(he, w2, epack, E, 4);  // s_e -> epack.x

        edge_pass_kernel<<<gEdge, BLK, 0, stream>>>(eptr, enode, s_n, epack, xl, e_out, E);
        node_pass_kernel<<<gNode, BLK, 0, stream>>>(nptr, nedge, s_n, epack, e_out, b, h, N);
    }

    // ---- pooling + head ----
    pool_head_kernel<<<G, BLK, 0, stream>>>(h, batch, N, proj_W, proj_b, out_W, out_b, out);
}

// Round 9
// 1382.895 us; speedup vs baseline: 2.6300x; 1.1479x over previous
//
#include <hip/hip_runtime.h>
#include <hip/hip_bf16.h>
#include <limits.h>
#include <math.h>

#define F_IN 92
#define H 35
#define HOUT 64
#define NL 3
#define NEG_SLOPE 0.2f
#define NSLICE 8
#define SCH 2048   // scan chunk per block (256 thr x 8)

typedef int iv4 __attribute__((ext_vector_type(4)));   // clang vector: valid for nontemporal builtins

// ------------------------------------------------------------------
// dense kernels
// ------------------------------------------------------------------

// h[n,j] = sum_k x[n,k] * W[k,j] + b[j]   (W: F_IN x H)
__global__ void embed_kernel(const float* __restrict__ x, const float* __restrict__ W,
                             const float* __restrict__ b, float* __restrict__ h, int N) {
    __shared__ float sW[F_IN * H];
    for (int t = threadIdx.x; t < F_IN * H; t += blockDim.x) sW[t] = W[t];
    __syncthreads();
    int total = N * H;
    int stride = gridDim.x * blockDim.x;
    for (int t = blockIdx.x * blockDim.x + threadIdx.x; t < total; t += stride) {
        int n = t / H, j = t - n * H;
        const float* xr = x + (long)n * F_IN;
        float acc = b[j];
#pragma unroll 4
        for (int k = 0; k < F_IN; ++k) acc += xr[k] * sW[k * H + j];
        h[t] = acc;
    }
}

// out[r,j] = sum_k in[r,k] * W[k,j]   (W: H x H, no bias)
__global__ void lin_kernel(const float* __restrict__ in, const float* __restrict__ W,
                           float* __restrict__ out, int R) {
    __shared__ float sW[H * H];
    for (int t = threadIdx.x; t < H * H; t += blockDim.x) sW[t] = W[t];
    __syncthreads();
    int total = R * H;
    int stride = gridDim.x * blockDim.x;
    for (int t = blockIdx.x * blockDim.x + threadIdx.x; t < total; t += stride) {
        int r = t / H, j = t - r * H;
        const float* ir = in + (long)r * H;
        float acc = 0.f;
#pragma unroll
        for (int k = 0; k < H; ++k) acc += ir[k] * sW[k * H + j];
        out[t] = acc;
    }
}

// s[r] = dot(in[r,:], vec[0:H])  -> s[r*stride_out]
__global__ void rowdot_kernel(const float* __restrict__ in, const float* __restrict__ vec,
                              float* __restrict__ s, int R, int stride_out) {
    __shared__ float sA[H];
    for (int t = threadIdx.x; t < H; t += blockDim.x) sA[t] = vec[t];
    __syncthreads();
    int stride = gridDim.x * blockDim.x;
    for (int r = blockIdx.x * blockDim.x + threadIdx.x; r < R; r += stride) {
        const float* xr = in + (long)r * H;
        float acc = 0.f;
#pragma unroll
        for (int k = 0; k < H; ++k) acc += xr[k] * sA[k];
        s[(long)r * stride_out] = acc;
    }
}

// w2[k] = sum_j W[k,j] * a[j]   (tiny: folds lin+att on hyperedge_attr)
__global__ void wfold_kernel(const float* __restrict__ W, const float* __restrict__ a,
                             float* __restrict__ w2) {
    int k = threadIdx.x;
    if (k < H) {
        float acc = 0.f;
#pragma unroll
        for (int j = 0; j < H; ++j) acc += W[k * H + j] * a[j];
        w2[k] = acc;
    }
}

// ------------------------------------------------------------------
// CSR build — destination-sliced scatter (validated r8) + hierarchical scan
// ------------------------------------------------------------------

__global__ void count_sliced_kernel(const int* __restrict__ ni, const int* __restrict__ ei,
                                    int* __restrict__ ncnt, int* __restrict__ ecnt,
                                    int ninc, int wN, int wE) {
    int s = blockIdx.x & (NSLICE - 1);
    int loN = s * wN, hiN = loN + wN;
    int loE = s * wE, hiE = loE + wE;
    int nblk = gridDim.x >> 3;
    int bid = blockIdx.x >> 3;
    int nvec = ninc >> 2;
    int stride = nblk * blockDim.x;
    for (int q = bid * blockDim.x + threadIdx.x; q < nvec; q += stride) {
        iv4 v4 = __builtin_nontemporal_load((const iv4*)ni + q);
        iv4 e4 = __builtin_nontemporal_load((const iv4*)ei + q);
#pragma unroll
        for (int u = 0; u < 4; ++u) {
            int e = e4[u], v = v4[u];
            if (e >= loE && e < hiE) atomicAdd(&ecnt[e], 1);
            if (v >= loN && v < hiN) atomicAdd(&ncnt[v], 1);
        }
    }
    if (bid == 0) {
        for (int i = (nvec << 2) + threadIdx.x; i < ninc; i += blockDim.x) {
            int v = ni[i], e = ei[i];
            if (e >= loE && e < hiE) atomicAdd(&ecnt[e], 1);
            if (v >= loN && v < hiN) atomicAdd(&ncnt[v], 1);
        }
    }
}

__device__ __forceinline__ int wave_sum_i(int s) {
#pragma unroll
    for (int off = 32; off; off >>= 1) s += __shfl_xor(s, off);
    return s;
}

// partial sums: blocks [0,nb0) cover cnt0 chunks, [nb0, nb0+nb1) cover cnt1
__global__ void bsum2_kernel(const int* __restrict__ cnt0, int nb0, int n0,
                             const int* __restrict__ cnt1, int n1,
                             int* __restrict__ bsums) {
    int b = blockIdx.x;
    const int* c; int n; int base;
    if (b < nb0) { c = cnt0; n = n0; base = b * SCH; }
    else         { c = cnt1; n = n1; base = (b - nb0) * SCH; }
    int t = threadIdx.x;
    int hi = base + SCH; if (hi > n) hi = n;
    int s = 0;
    for (int i = base + t; i < hi; i += 256) s += c[i];
    s = wave_sum_i(s);
    __shared__ int ws[4];
    if ((t & 63) == 0) ws[t >> 6] = s;
    __syncthreads();
    if (t == 0) bsums[b] = ws[0] + ws[1] + ws[2] + ws[3];
}

// tiny serial exclusive scan of the block sums (both arrays)
__global__ void scan_bsums_kernel(int* __restrict__ bsums, int nb0, int nb1) {
    int t = threadIdx.x;
    if (t == 0) {
        int acc = 0;
        for (int i = 0; i < nb0; ++i) { int v = bsums[i]; bsums[i] = acc; acc += v; }
    } else if (t == 1) {
        int acc = 0;
        for (int i = nb0; i < nb0 + nb1; ++i) { int v = bsums[i]; bsums[i] = acc; acc += v; }
    }
}

// block-local exclusive scan + offset; writes ptr and cur; ptr[n] = ninc
__global__ void scan_write2_kernel(const int* __restrict__ cnt0, int* __restrict__ ptr0,
                                   int* __restrict__ cur0, int nb0, int n0,
                                   const int* __restrict__ cnt1, int* __restrict__ ptr1,
                                   int* __restrict__ cur1, int n1,
                                   const int* __restrict__ bsums, int ninc) {
    int b = blockIdx.x;
    const int* c; int* p; int* u; int n; int base;
    if (b < nb0) { c = cnt0; p = ptr0; u = cur0; n = n0; base = b * SCH; }
    else         { c = cnt1; p = ptr1; u = cur1; n = n1; base = (b - nb0) * SCH; }
    int off = bsums[b];
    int t = threadIdx.x;
    int lo = base + t * 8;
    int vals[8];
    int s = 0;
#pragma unroll
    for (int k = 0; k < 8; ++k) {
        int i = lo + k;
        int v = (i < n) ? c[i] : 0;
        vals[k] = s;         // local exclusive prefix
        s += v;
    }
    __shared__ int lds[256];
    lds[t] = s;
    __syncthreads();
    for (int o2 = 1; o2 < 256; o2 <<= 1) {
        int v = (t >= o2) ? lds[t - o2] : 0;
        __syncthreads();
        lds[t] += v;
        __syncthreads();
    }
    int tbase = off + ((t == 0) ? 0 : lds[t - 1]);
#pragma unroll
    for (int k = 0; k < 8; ++k) {
        int i = lo + k;
        if (i < n) { int val = tbase + vals[k]; p[i] = val; u[i] = val; }
    }
    if (b == 0 && t == 0) { ptr0[n0] = ninc; ptr1[n1] = ninc; }
}

// sliced counting-sort fill: slice s handles scatter targets in its id-range only
__global__ void csr_fill_sliced_kernel(const int* __restrict__ ni, const int* __restrict__ ei,
                                       int* __restrict__ ecur, int* __restrict__ ncur,
                                       int* __restrict__ enode, int* __restrict__ nedge,
                                       int ninc, int wN, int wE) {
    int s = blockIdx.x & (NSLICE - 1);
    int loN = s * wN, hiN = loN + wN;
    int loE = s * wE, hiE = loE + wE;
    int nblk = gridDim.x >> 3;
    int bid = blockIdx.x >> 3;
    int nvec = ninc >> 2;
    int stride = nblk * blockDim.x;
    for (int q = bid * blockDim.x + threadIdx.x; q < nvec; q += stride) {
        iv4 v4 = __builtin_nontemporal_load((const iv4*)ni + q);
        iv4 e4 = __builtin_nontemporal_load((const iv4*)ei + q);
#pragma unroll
        for (int u = 0; u < 4; ++u) {
            int e = e4[u], v = v4[u];
            if (e >= loE && e < hiE) {
                int p = atomicAdd(&ecur[e], 1);
                enode[p] = v;
            }
            if (v >= loN && v < hiN) {
                int p = atomicAdd(&ncur[v], 1);
                nedge[p] = e;
            }
        }
    }
    if (bid == 0) {
        for (int i = (nvec << 2) + threadIdx.x; i < ninc; i += blockDim.x) {
            int v = ni[i], e = ei[i];
            if (e >= loE && e < hiE) { int p = atomicAdd(&ecur[e], 1); enode[p] = v; }
            if (v >= loN && v < hiN) { int p = atomicAdd(&ncur[v], 1); nedge[p] = e; }
        }
    }
}

// ------------------------------------------------------------------
// fused sparse passes (atomic-free, 1 wave per segment, single-load,
// LDS-broadcast inner gather)
// ------------------------------------------------------------------

__device__ __forceinline__ float wave_max(float m) {
#pragma unroll
    for (int off = 32; off; off >>= 1) m = fmaxf(m, __shfl_xor(m, off));
    return m;
}
__device__ __forceinline__ float wave_sum(float s) {
#pragma unroll
    for (int off = 32; off; off >>= 1) s += __shfl_xor(s, off);
    return s;
}

// per edge e: softmax over incident nodes + weighted accumulation into e_out[e,:]
// epack[e] = {s_e, m, 1/(sum+eps), -}; reads epack.x, writes .y/.z
__global__ void edge_pass_kernel(const int* __restrict__ eptr, const int* __restrict__ enode,
                                 const float* __restrict__ s_n, float* __restrict__ epack,
                                 const float* __restrict__ xl,
                                 float* __restrict__ e_out, int E) {
    __shared__ float shA[4][64];
    __shared__ int   shV[4][64];
    int lane = threadIdx.x & 63;
    int ws = threadIdx.x >> 6;
    int wid = (blockIdx.x * blockDim.x + threadIdx.x) >> 6;
    int nw = (gridDim.x * blockDim.x) >> 6;
    for (int e = wid; e < E; e += nw) {
        int lo = eptr[e], hi = eptr[e + 1];
        int deg = hi - lo;
        float se = epack[4 * (long)e];
        float binv = deg > 0 ? 1.f / (float)deg : 0.f;
        float acc = 0.f;
        float mm, rec;
        if (deg <= 64) {
            int v = 0; float sc = -INFINITY;
            if (lane < deg) {
                v = enode[lo + lane];
                sc = s_n[v] + se;
                sc = sc >= 0.f ? sc : NEG_SLOPE * sc;
            }
            float m = wave_max(sc);
            mm = (m == -INFINITY) ? 0.f : m;
            float ex = (lane < deg) ? expf(sc - mm) : 0.f;
            float s = wave_sum(ex);
            rec = 1.f / (s + 1e-16f);
            shA[ws][lane] = ex * rec * binv;
            shV[ws][lane] = v;
#pragma unroll 4
            for (int k = 0; k < deg; ++k) {
                float ak = shA[ws][k];
                int vk = shV[ws][k];
                if (lane < H) acc += ak * xl[(long)vk * H + lane];
            }
        } else {
            float m = -INFINITY;
            for (int k = lo + lane; k < hi; k += 64) {
                float sc = s_n[enode[k]] + se;
                sc = sc >= 0.f ? sc : NEG_SLOPE * sc;
                m = fmaxf(m, sc);
            }
            m = wave_max(m);
            mm = (m == -INFINITY) ? 0.f : m;
            float s = 0.f;
            for (int k = lo + lane; k < hi; k += 64) {
                float sc = s_n[enode[k]] + se;
                sc = sc >= 0.f ? sc : NEG_SLOPE * sc;
                s += expf(sc - mm);
            }
            s = wave_sum(s);
            rec = 1.f / (s + 1e-16f);
            float cb = rec * binv;
            for (int base = lo; base < hi; base += 64) {
                int v = 0; float a = 0.f;
                if (base + lane < hi) {
                    v = enode[base + lane];
                    float sc = s_n[v] + se;
                    sc = sc >= 0.f ? sc : NEG_SLOPE * sc;
                    a = expf(sc - mm) * cb;
                }
                shA[ws][lane] = a;
                shV[ws][lane] = v;
                int cn = hi - base; if (cn > 64) cn = 64;
#pragma unroll 4
                for (int k = 0; k < cn; ++k) {
                    float ak = shA[ws][k];
                    int vk = shV[ws][k];
                    if (lane < H) acc += ak * xl[(long)vk * H + lane];
                }
            }
        }
        if (lane < H) e_out[(long)e * H + lane] = acc;
        if (lane == 0) { epack[4 * (long)e + 1] = mm; epack[4 * (long)e + 2] = rec; }
    }
}

// per node v: h[v,j] = Dinv * sum_i alpha_i * e_out[e_i, j] + bias[j]
__global__ void node_pass_kernel(const int* __restrict__ nptr, const int* __restrict__ nedge,
                                 const float* __restrict__ s_n, const float* __restrict__ epack,
                                 const float* __restrict__ e_out, const float* __restrict__ bias,
                                 float* __restrict__ hout, int N) {
    __shared__ float shA[4][64];
    __shared__ int   shE[4][64];
    int lane = threadIdx.x & 63;
    int ws = threadIdx.x >> 6;
    int wid = (blockIdx.x * blockDim.x + threadIdx.x) >> 6;
    int nw = (gridDim.x * blockDim.x) >> 6;
    for (int v = wid; v < N; v += nw) {
        int lo = nptr[v], hi = nptr[v + 1];
        int deg = hi - lo;
        float dinv = deg > 0 ? 1.f / (float)deg : 0.f;
        float sn = s_n[v];
        float acc = 0.f;
        if (deg <= 64) {
            int e = 0; float a = 0.f;
            if (lane < deg) {
                e = nedge[lo + lane];
                float4 p = ((const float4*)epack)[e];   // {s_e, m, rec, -} one 16B gather
                float sc = sn + p.x;
                sc = sc >= 0.f ? sc : NEG_SLOPE * sc;
                a = expf(sc - p.y) * p.z;
            }
            shA[ws][lane] = a;
            shE[ws][lane] = e;
#pragma unroll 4
            for (int k = 0; k < deg; ++k) {
                float ak = shA[ws][k];
                int ek = shE[ws][k];
                if (lane < H) acc += ak * e_out[(long)ek * H + lane];
            }
        } else {
            for (int base = lo; base < hi; base += 64) {
                int e = 0; float a = 0.f;
                if (base + lane < hi) {
                    e = nedge[base + lane];
                    float4 p = ((const float4*)epack)[e];
                    float sc = sn + p.x;
                    sc = sc >= 0.f ? sc : NEG_SLOPE * sc;
                    a = expf(sc - p.y) * p.z;
                }
                shA[ws][lane] = a;
                shE[ws][lane] = e;
                int cn = hi - base; if (cn > 64) cn = 64;
#pragma unroll 4
                for (int k = 0; k < cn; ++k) {
                    float ak = shA[ws][k];
                    int ek = shE[ws][k];
                    if (lane < H) acc += ak * e_out[(long)ek * H + lane];
                }
            }
        }
        if (lane < H) hout[(long)v * H + lane] = dinv * acc + bias[lane];
    }
}

// ------------------------------------------------------------------
// fused pooling (batch sorted -> binary search) + MLP head
// ------------------------------------------------------------------
__global__ void pool_head_kernel(const float* __restrict__ h, const int* __restrict__ batch,
                                 int N, const float* __restrict__ pW, const float* __restrict__ pb,
                                 const float* __restrict__ oW, const float* __restrict__ ob,
                                 float* __restrict__ out) {
    int g = blockIdx.x;
    int t = threadIdx.x;
    __shared__ int bounds[2];
    __shared__ float partial[7][H];
    __shared__ float pooled[H];
    if (t == 0) {
        int lo = 0, hi = N;
        while (lo < hi) { int mid = (lo + hi) >> 1; if (batch[mid] < g) lo = mid + 1; else hi = mid; }
        bounds[0] = lo;
        int lo2 = lo, hi2 = N;
        while (lo2 < hi2) { int mid = (lo2 + hi2) >> 1; if (batch[mid] < g + 1) lo2 = mid + 1; else hi2 = mid; }
        bounds[1] = lo2;
    }
    __syncthreads();
    int rlo = bounds[0], rhi = bounds[1];
    int cntg = rhi - rlo;
    int gg = t / H;
    int j = t - gg * H;
    if (gg < 7) {
        float acc = 0.f;
        for (int r = rlo + gg; r < rhi; r += 7) acc += h[(long)r * H + j];
        partial[gg][j] = acc;
    }
    __syncthreads();
    if (t < H) {
        float s = 0.f;
#pragma unroll
        for (int k = 0; k < 7; ++k) s += partial[k][t];
        pooled[t] = s / fmaxf((float)cntg, 1.f);
    }
    __syncthreads();
    if (t < HOUT) {
        float acc = pb[t];
#pragma unroll
        for (int k = 0; k < H; ++k) acc += pooled[k] * pW[k * HOUT + t];
        float z = fmaxf(acc, 0.f) + log1pf(expf(-fabsf(acc)));  // softplus
        float pr = z * oW[t];
#pragma unroll
        for (int off = 32; off; off >>= 1) pr += __shfl_down(pr, off);
        if (t == 0) out[g] = pr + ob[0];
    }
}

static inline int grid_for(long n, int block = 256, long cap = 2048) {
    long b = (n + block - 1) / block;
    if (b > cap) b = cap;
    if (b < 1) b = 1;
    return (int)b;
}

extern "C" void kernel_launch(void* const* d_in, const int* in_sizes, int n_in,
                              void* d_out, int out_size, void* d_ws, size_t ws_size,
                              hipStream_t stream) {
    const float* x       = (const float*)d_in[0];
    const float* he      = (const float*)d_in[1];
    const int*   ni      = (const int*)d_in[2];
    const int*   ei      = (const int*)d_in[3];
    const int*   batch   = (const int*)d_in[4];
    const float* embed_W = (const float*)d_in[5];
    const float* embed_b = (const float*)d_in[6];
    const float* lin_W   = (const float*)d_in[7];   // [L,H,H]
    const float* att     = (const float*)d_in[8];   // [L,2H]
    const float* conv_b  = (const float*)d_in[9];   // [L,H]
    const float* proj_W  = (const float*)d_in[10];  // [H,HOUT]
    const float* proj_b  = (const float*)d_in[11];
    const float* out_W   = (const float*)d_in[12];  // [HOUT,1]
    const float* out_b   = (const float*)d_in[13];
    float* out = (float*)d_out;

    const int N    = in_sizes[0] / F_IN;  // 100000
    const int E    = in_sizes[1] / H;     // 50000
    const int NINC = in_sizes[2];         // 2000000
    const int G    = out_size;            // 256

    char* w = (char*)d_ws;
    auto alloc = [&](size_t bytes) {
        char* p = w;
        w += (bytes + 255) & ~(size_t)255;
        return p;
    };
    float* h     = (float*)alloc((size_t)N * H * 4);
    float* xl    = (float*)alloc((size_t)N * H * 4);
    float* e_out = (float*)alloc((size_t)E * H * 4);
    float* s_n   = (float*)alloc((size_t)N * 4);
    float* epack = (float*)alloc((size_t)E * 16);   // float4 {s_e, m, rec, -}
    float* w2    = (float*)alloc((size_t)H * 4);
    int*   ecnt  = (int*)alloc((size_t)E * 4);
    int*   eptr  = (int*)alloc((size_t)(E + 1) * 4);
    int*   ecur  = (int*)alloc((size_t)E * 4);
    int*   ncnt  = (int*)alloc((size_t)N * 4);
    int*   nptr  = (int*)alloc((size_t)(N + 1) * 4);
    int*   ncur  = (int*)alloc((size_t)N * 4);
    int*   enode = (int*)alloc((size_t)NINC * 4);
    int*   nedge = (int*)alloc((size_t)NINC * 4);
    int*   bsums = (int*)alloc((size_t)256 * 4);

    const int BLK = 256;
    int gNH  = grid_for((long)N * H);
    int gN   = grid_for(N);
    int gE   = grid_for(E);
    int wN   = (N + NSLICE - 1) / NSLICE;   // 12500
    int wE   = (E + NSLICE - 1) / NSLICE;   // 6250
    int nbE  = (E + SCH - 1) / SCH;         // 25
    int nbN  = (N + SCH - 1) / SCH;         // 49

    // ---- CSR build (once; same incidence structure for all layers) ----
    (void)hipMemsetAsync(ncnt, 0, (size_t)N * 4, stream);
    (void)hipMemsetAsync(ecnt, 0, (size_t)E * 4, stream);
    count_sliced_kernel<<<2048, BLK, 0, stream>>>(ni, ei, ncnt, ecnt, NINC, wN, wE);
    // hierarchical dual scan: ecnt -> eptr/ecur, ncnt -> nptr/ncur
    bsum2_kernel<<<nbE + nbN, 256, 0, stream>>>(ecnt, nbE, E, ncnt, N, bsums);
    scan_bsums_kernel<<<1, 64, 0, stream>>>(bsums, nbE, nbN);
    scan_write2_kernel<<<nbE + nbN, 256, 0, stream>>>(ecnt, eptr, ecur, nbE, E,
                                                      ncnt, nptr, ncur, N, bsums, NINC);
    csr_fill_sliced_kernel<<<2048, BLK, 0, stream>>>(ni, ei, ecur, ncur, enode, nedge,
                                                     NINC, wN, wE);

    // ---- embed ----
    embed_kernel<<<gNH, BLK, 0, stream>>>(x, embed_W, embed_b, h, N);

    // ---- layers ----
    int gEdge = (E + 3) / 4;   // 1 wave per edge
    int gNode = (N + 3) / 4;   // 1 wave per node
    for (int l = 0; l < NL; ++l) {
        const float* W  = lin_W + (size_t)l * H * H;
        const float* at = att + (size_t)l * 2 * H;
        const float* b  = conv_b + (size_t)l * H;

        lin_kernel<<<gNH, BLK, 0, stream>>>(h, W, xl, N);
        rowdot_kernel<<<gN, BLK, 0, stream>>>(xl, at, s_n, N, 1);
        wfold_kernel<<<1, 64, 0, stream>>>(W, at + H, w2);
        rowdot_kernel<<<gE, BLK, 0, stream>>>(he, w2, epack, E, 4);  // s_e -> epack.x

        edge_pass_kernel<<<gEdge, BLK, 0, stream>>>(eptr, enode, s_n, epack, xl, e_out, E);
        node_pass_kernel<<<gNode, BLK, 0, stream>>>(nptr, nedge, s_n, epack, e_out, b, h, N);
    }

    // ---- pooling + head ----
    pool_head_kernel<<<G, BLK, 0, stream>>>(h, batch, N, proj_W, proj_b, out_W, out_b, out);
}

// Round 13
// 1014.372 us; speedup vs baseline: 3.5854x; 1.3633x over previous
//
#include <hip/hip_runtime.h>
#include <hip/hip_bf16.h>
#include <limits.h>
#include <math.h>

#define F_IN 92
#define H 35
#define HP 36        // padded row stride: 144 B = 9 x float4, 16B-aligned
#define HOUT 64
#define NL 3
#define NEG_SLOPE 0.2f
#define NSLICE 8
#define SCH 2048     // scan chunk per block (256 thr x 8)

typedef int iv4 __attribute__((ext_vector_type(4)));

// ------------------------------------------------------------------
// dense kernels (feature rows padded to HP; pad col written as 0)
// ------------------------------------------------------------------

// h[n,j] = sum_k x[n,k] * W[k,j] + b[j]   (W: F_IN x H), h stride HP
__global__ void embed_kernel(const float* __restrict__ x, const float* __restrict__ W,
                             const float* __restrict__ b, float* __restrict__ h, int N) {
    __shared__ float sW[F_IN * H];
    for (int t = threadIdx.x; t < F_IN * H; t += blockDim.x) sW[t] = W[t];
    __syncthreads();
    int total = N * HP;
    int stride = gridDim.x * blockDim.x;
    for (int t = blockIdx.x * blockDim.x + threadIdx.x; t < total; t += stride) {
        int n = t / HP, j = t - n * HP;
        if (j < H) {
            const float* xr = x + (long)n * F_IN;
            float acc = b[j];
#pragma unroll 4
            for (int k = 0; k < F_IN; ++k) acc += xr[k] * sW[k * H + j];
            h[t] = acc;
        } else {
            h[t] = 0.f;
        }
    }
}

// out[r,j] = sum_k in[r,k] * W[k,j]   (W: H x H), in/out stride HP
__global__ void lin_kernel(const float* __restrict__ in, const float* __restrict__ W,
                           float* __restrict__ out, int R) {
    __shared__ float sW[H * H];
    for (int t = threadIdx.x; t < H * H; t += blockDim.x) sW[t] = W[t];
    __syncthreads();
    int total = R * HP;
    int stride = gridDim.x * blockDim.x;
    for (int t = blockIdx.x * blockDim.x + threadIdx.x; t < total; t += stride) {
        int r = t / HP, j = t - r * HP;
        if (j < H) {
            const float* ir = in + (long)r * HP;
            float acc = 0.f;
#pragma unroll
            for (int k = 0; k < H; ++k) acc += ir[k] * sW[k * H + j];
            out[t] = acc;
        } else {
            out[t] = 0.f;
        }
    }
}

// s[r] = dot(in[r,:], vec[0:H])  -> s[r*stride_out]; in stride HP
__global__ void rowdot_kernel(const float* __restrict__ in, const float* __restrict__ vec,
                              float* __restrict__ s, int R, int stride_out) {
    __shared__ float sA[H];
    for (int t = threadIdx.x; t < H; t += blockDim.x) sA[t] = vec[t];
    __syncthreads();
    int stride = gridDim.x * blockDim.x;
    for (int r = blockIdx.x * blockDim.x + threadIdx.x; r < R; r += stride) {
        const float* xr = in + (long)r * HP;
        float acc = 0.f;
#pragma unroll
        for (int k = 0; k < H; ++k) acc += xr[k] * sA[k];
        s[(long)r * stride_out] = acc;
    }
}

// he_s[r] = dot(he[r,:], vec)  (he is UNPADDED stride H from input)
__global__ void rowdot_he_kernel(const float* __restrict__ in, const float* __restrict__ vec,
                                 float* __restrict__ s, int R, int stride_out) {
    __shared__ float sA[H];
    for (int t = threadIdx.x; t < H; t += blockDim.x) sA[t] = vec[t];
    __syncthreads();
    int stride = gridDim.x * blockDim.x;
    for (int r = blockIdx.x * blockDim.x + threadIdx.x; r < R; r += stride) {
        const float* xr = in + (long)r * H;
        float acc = 0.f;
#pragma unroll
        for (int k = 0; k < H; ++k) acc += xr[k] * sA[k];
        s[(long)r * stride_out] = acc;
    }
}

// w2[k] = sum_j W[k,j] * a[j]
__global__ void wfold_kernel(const float* __restrict__ W, const float* __restrict__ a,
                             float* __restrict__ w2) {
    int k = threadIdx.x;
    if (k < H) {
        float acc = 0.f;
#pragma unroll
        for (int j = 0; j < H; ++j) acc += W[k * H + j] * a[j];
        w2[k] = acc;
    }
}

// ------------------------------------------------------------------
// CSR build — sliced scatter (r8) + hierarchical scan (r9), both validated
// ------------------------------------------------------------------

__global__ void count_sliced_kernel(const int* __restrict__ ni, const int* __restrict__ ei,
                                    int* __restrict__ ncnt, int* __restrict__ ecnt,
                                    int ninc, int wN, int wE) {
    int s = blockIdx.x & (NSLICE - 1);
    int loN = s * wN, hiN = loN + wN;
    int loE = s * wE, hiE = loE + wE;
    int nblk = gridDim.x >> 3;
    int bid = blockIdx.x >> 3;
    int nvec = ninc >> 2;
    int stride = nblk * blockDim.x;
    for (int q = bid * blockDim.x + threadIdx.x; q < nvec; q += stride) {
        iv4 v4 = __builtin_nontemporal_load((const iv4*)ni + q);
        iv4 e4 = __builtin_nontemporal_load((const iv4*)ei + q);
#pragma unroll
        for (int u = 0; u < 4; ++u) {
            int e = e4[u], v = v4[u];
            if (e >= loE && e < hiE) atomicAdd(&ecnt[e], 1);
            if (v >= loN && v < hiN) atomicAdd(&ncnt[v], 1);
        }
    }
    if (bid == 0) {
        for (int i = (nvec << 2) + threadIdx.x; i < ninc; i += blockDim.x) {
            int v = ni[i], e = ei[i];
            if (e >= loE && e < hiE) atomicAdd(&ecnt[e], 1);
            if (v >= loN && v < hiN) atomicAdd(&ncnt[v], 1);
        }
    }
}

__device__ __forceinline__ int wave_sum_i(int s) {
#pragma unroll
    for (int off = 32; off; off >>= 1) s += __shfl_xor(s, off);
    return s;
}

__global__ void bsum2_kernel(const int* __restrict__ cnt0, int nb0, int n0,
                             const int* __restrict__ cnt1, int n1,
                             int* __restrict__ bsums) {
    int b = blockIdx.x;
    const int* c; int n; int base;
    if (b < nb0) { c = cnt0; n = n0; base = b * SCH; }
    else         { c = cnt1; n = n1; base = (b - nb0) * SCH; }
    int t = threadIdx.x;
    int hi = base + SCH; if (hi > n) hi = n;
    int s = 0;
    for (int i = base + t; i < hi; i += 256) s += c[i];
    s = wave_sum_i(s);
    __shared__ int ws[4];
    if ((t & 63) == 0) ws[t >> 6] = s;
    __syncthreads();
    if (t == 0) bsums[b] = ws[0] + ws[1] + ws[2] + ws[3];
}

__global__ void scan_bsums_kernel(int* __restrict__ bsums, int nb0, int nb1) {
    int t = threadIdx.x;
    if (t == 0) {
        int acc = 0;
        for (int i = 0; i < nb0; ++i) { int v = bsums[i]; bsums[i] = acc; acc += v; }
    } else if (t == 1) {
        int acc = 0;
        for (int i = nb0; i < nb0 + nb1; ++i) { int v = bsums[i]; bsums[i] = acc; acc += v; }
    }
}

__global__ void scan_write2_kernel(const int* __restrict__ cnt0, int* __restrict__ ptr0,
                                   int* __restrict__ cur0, int nb0, int n0,
                                   const int* __restrict__ cnt1, int* __restrict__ ptr1,
                                   int* __restrict__ cur1, int n1,
                                   const int* __restrict__ bsums, int ninc) {
    int b = blockIdx.x;
    const int* c; int* p; int* u; int n; int base;
    if (b < nb0) { c = cnt0; p = ptr0; u = cur0; n = n0; base = b * SCH; }
    else         { c = cnt1; p = ptr1; u = cur1; n = n1; base = (b - nb0) * SCH; }
    int off = bsums[b];
    int t = threadIdx.x;
    int lo = base + t * 8;
    int vals[8];
    int s = 0;
#pragma unroll
    for (int k = 0; k < 8; ++k) {
        int i = lo + k;
        int v = (i < n) ? c[i] : 0;
        vals[k] = s;
        s += v;
    }
    __shared__ int lds[256];
    lds[t] = s;
    __syncthreads();
    for (int o2 = 1; o2 < 256; o2 <<= 1) {
        int v = (t >= o2) ? lds[t - o2] : 0;
        __syncthreads();
        lds[t] += v;
        __syncthreads();
    }
    int tbase = off + ((t == 0) ? 0 : lds[t - 1]);
#pragma unroll
    for (int k = 0; k < 8; ++k) {
        int i = lo + k;
        if (i < n) { int val = tbase + vals[k]; p[i] = val; u[i] = val; }
    }
    if (b == 0 && t == 0) { ptr0[n0] = ninc; ptr1[n1] = ninc; }
}

__global__ void csr_fill_sliced_kernel(const int* __restrict__ ni, const int* __restrict__ ei,
                                       int* __restrict__ ecur, int* __restrict__ ncur,
                                       int* __restrict__ enode, int* __restrict__ nedge,
                                       int ninc, int wN, int wE) {
    int s = blockIdx.x & (NSLICE - 1);
    int loN = s * wN, hiN = loN + wN;
    int loE = s * wE, hiE = loE + wE;
    int nblk = gridDim.x >> 3;
    int bid = blockIdx.x >> 3;
    int nvec = ninc >> 2;
    int stride = nblk * blockDim.x;
    for (int q = bid * blockDim.x + threadIdx.x; q < nvec; q += stride) {
        iv4 v4 = __builtin_nontemporal_load((const iv4*)ni + q);
        iv4 e4 = __builtin_nontemporal_load((const iv4*)ei + q);
#pragma unroll
        for (int u = 0; u < 4; ++u) {
            int e = e4[u], v = v4[u];
            if (e >= loE && e < hiE) {
                int p = atomicAdd(&ecur[e], 1);
                enode[p] = v;
            }
            if (v >= loN && v < hiN) {
                int p = atomicAdd(&ncur[v], 1);
                nedge[p] = e;
            }
        }
    }
    if (bid == 0) {
        for (int i = (nvec << 2) + threadIdx.x; i < ninc; i += blockDim.x) {
            int v = ni[i], e = ei[i];
            if (e >= loE && e < hiE) { int p = atomicAdd(&ecur[e], 1); enode[p] = v; }
            if (v >= loN && v < hiN) { int p = atomicAdd(&ncur[v], 1); nedge[p] = e; }
        }
    }
}

// ------------------------------------------------------------------
// fused sparse passes — 7 groups x 9 lanes, per-lane float4 gathers
// (63 independent loads in flight per wave vs 1 broadcast row before)
// ------------------------------------------------------------------

__device__ __forceinline__ float wave_max(float m) {
#pragma unroll
    for (int off = 32; off; off >>= 1) m = fmaxf(m, __shfl_xor(m, off));
    return m;
}
__device__ __forceinline__ float wave_sum(float s) {
#pragma unroll
    for (int off = 32; off; off >>= 1) s += __shfl_xor(s, off);
    return s;
}

// grouped gather-accumulate: rows k≡g (mod 7) from src (stride HP), coeffs in shA/shV
__device__ __forceinline__ void grouped_gather(const float* __restrict__ src,
                                               const float* shA, const int* shV,
                                               int cnt, int g, int l, float4& acc) {
    if (g < 7) {
        for (int k = g; k < cnt; k += 7) {
            float ak = shA[k];
            int vk = shV[k];
            float4 xv = ((const float4*)(src + (size_t)vk * HP))[l];
            acc.x += ak * xv.x; acc.y += ak * xv.y;
            acc.z += ak * xv.z; acc.w += ak * xv.w;
        }
    }
}

// cross-group reduce: lanes 0..8 end with the total for their col-chunk
__device__ __forceinline__ void group_reduce(float4& acc, int lane, int l) {
#pragma unroll
    for (int gg = 1; gg < 7; ++gg) {
        int src = l + 9 * gg;
        float ox = __shfl(acc.x, src);
        float oy = __shfl(acc.y, src);
        float oz = __shfl(acc.z, src);
        float ow = __shfl(acc.w, src);
        if (lane < 9) { acc.x += ox; acc.y += oy; acc.z += oz; acc.w += ow; }
    }
}

// per edge e: softmax + weighted accumulation into e_out[e,:] (stride HP)
__global__ void edge_pass_kernel(const int* __restrict__ eptr, const int* __restrict__ enode,
                                 const float* __restrict__ s_n, float* __restrict__ epack,
                                 const float* __restrict__ xl,
                                 float* __restrict__ e_out, int E) {
    __shared__ float shA[4][64];
    __shared__ int   shV[4][64];
    int lane = threadIdx.x & 63;
    int ws = threadIdx.x >> 6;
    int g = lane / 9, l = lane - g * 9;
    int wid = (blockIdx.x * blockDim.x + threadIdx.x) >> 6;
    int nw = (gridDim.x * blockDim.x) >> 6;
    for (int e = wid; e < E; e += nw) {
        int lo = eptr[e], hi = eptr[e + 1];
        int deg = hi - lo;
        float se = epack[4 * (long)e];
        float binv = deg > 0 ? 1.f / (float)deg : 0.f;
        float4 acc = {0.f, 0.f, 0.f, 0.f};
        float mm, rec;
        if (deg <= 64) {
            int v = 0; float sc = -INFINITY;
            if (lane < deg) {
                v = enode[lo + lane];
                sc = s_n[v] + se;
                sc = sc >= 0.f ? sc : NEG_SLOPE * sc;
            }
            float m = wave_max(sc);
            mm = (m == -INFINITY) ? 0.f : m;
            float ex = (lane < deg) ? expf(sc - mm) : 0.f;
            float s = wave_sum(ex);
            rec = 1.f / (s + 1e-16f);
            shA[ws][lane] = ex * rec * binv;
            shV[ws][lane] = v;
            grouped_gather(xl, shA[ws], shV[ws], deg, g, l, acc);
        } else {
            float m = -INFINITY;
            for (int k = lo + lane; k < hi; k += 64) {
                float sc = s_n[enode[k]] + se;
                sc = sc >= 0.f ? sc : NEG_SLOPE * sc;
                m = fmaxf(m, sc);
            }
            m = wave_max(m);
            mm = (m == -INFINITY) ? 0.f : m;
            float s = 0.f;
            for (int k = lo + lane; k < hi; k += 64) {
                float sc = s_n[enode[k]] + se;
                sc = sc >= 0.f ? sc : NEG_SLOPE * sc;
                s += expf(sc - mm);
            }
            s = wave_sum(s);
            rec = 1.f / (s + 1e-16f);
            float cb = rec * binv;
            for (int base = lo; base < hi; base += 64) {
                int v = 0; float a = 0.f;
                if (base + lane < hi) {
                    v = enode[base + lane];
                    float sc = s_n[v] + se;
                    sc = sc >= 0.f ? sc : NEG_SLOPE * sc;
                    a = expf(sc - mm) * cb;
                }
                shA[ws][lane] = a;
                shV[ws][lane] = v;
                int cn = hi - base; if (cn > 64) cn = 64;
                grouped_gather(xl, shA[ws], shV[ws], cn, g, l, acc);
            }
        }
        group_reduce(acc, lane, l);
        if (lane < 9) ((float4*)(e_out + (size_t)e * HP))[lane] = acc;
        if (lane == 0) { epack[4 * (long)e + 1] = mm; epack[4 * (long)e + 2] = rec; }
    }
}

// per node v: h[v,:] = Dinv * sum alpha_i * e_out[e_i,:] + bias   (stride HP)
__global__ void node_pass_kernel(const int* __restrict__ nptr, const int* __restrict__ nedge,
                                 const float* __restrict__ s_n, const float* __restrict__ epack,
                                 const float* __restrict__ e_out, const float* __restrict__ bias,
                                 float* __restrict__ hout, int N) {
    __shared__ float shA[4][64];
    __shared__ int   shE[4][64];
    __shared__ float sb[HP];
    if (threadIdx.x < HP) sb[threadIdx.x] = (threadIdx.x < H) ? bias[threadIdx.x] : 0.f;
    __syncthreads();
    int lane = threadIdx.x & 63;
    int ws = threadIdx.x >> 6;
    int g = lane / 9, l = lane - g * 9;
    int wid = (blockIdx.x * blockDim.x + threadIdx.x) >> 6;
    int nw = (gridDim.x * blockDim.x) >> 6;
    for (int v = wid; v < N; v += nw) {
        int lo = nptr[v], hi = nptr[v + 1];
        int deg = hi - lo;
        float dinv = deg > 0 ? 1.f / (float)deg : 0.f;
        float sn = s_n[v];
        float4 acc = {0.f, 0.f, 0.f, 0.f};
        if (deg <= 64) {
            int e = 0; float a = 0.f;
            if (lane < deg) {
                e = nedge[lo + lane];
                float4 p = ((const float4*)epack)[e];
                float sc = sn + p.x;
                sc = sc >= 0.f ? sc : NEG_SLOPE * sc;
                a = expf(sc - p.y) * p.z;
            }
            shA[ws][lane] = a;
            shE[ws][lane] = e;
            grouped_gather(e_out, shA[ws], shE[ws], deg, g, l, acc);
        } else {
            for (int base = lo; base < hi; base += 64) {
                int e = 0; float a = 0.f;
                if (base + lane < hi) {
                    e = nedge[base + lane];
                    float4 p = ((const float4*)epack)[e];
                    float sc = sn + p.x;
                    sc = sc >= 0.f ? sc : NEG_SLOPE * sc;
                    a = expf(sc - p.y) * p.z;
                }
                shA[ws][lane] = a;
                shE[ws][lane] = e;
                int cn = hi - base; if (cn > 64) cn = 64;
                grouped_gather(e_out, shA[ws], shE[ws], cn, g, l, acc);
            }
        }
        group_reduce(acc, lane, l);
        if (lane < 9) {
            float4 bb = ((const float4*)sb)[lane];
            float4 r;
            r.x = dinv * acc.x + bb.x;
            r.y = dinv * acc.y + bb.y;
            r.z = dinv * acc.z + bb.z;
            r.w = dinv * acc.w + bb.w;
            ((float4*)(hout + (size_t)v * HP))[lane] = r;
        }
    }
}

// ------------------------------------------------------------------
// fused pooling (batch sorted -> binary search) + MLP head (h stride HP)
// ------------------------------------------------------------------
__global__ void pool_head_kernel(const float* __restrict__ h, const int* __restrict__ batch,
                                 int N, const float* __restrict__ pW, const float* __restrict__ pb,
                                 const float* __restrict__ oW, const float* __restrict__ ob,
                                 float* __restrict__ out) {
    int g = blockIdx.x;
    int t = threadIdx.x;
    __shared__ int bounds[2];
    __shared__ float partial[7][H];
    __shared__ float pooled[H];
    if (t == 0) {
        int lo = 0, hi = N;
        while (lo < hi) { int mid = (lo + hi) >> 1; if (batch[mid] < g) lo = mid + 1; else hi = mid; }
        bounds[0] = lo;
        int lo2 = lo, hi2 = N;
        while (lo2 < hi2) { int mid = (lo2 + hi2) >> 1; if (batch[mid] < g + 1) lo2 = mid + 1; else hi2 = mid; }
        bounds[1] = lo2;
    }
    __syncthreads();
    int rlo = bounds[0], rhi = bounds[1];
    int cntg = rhi - rlo;
    int gg = t / H;
    int j = t - gg * H;
    if (gg < 7) {
        float acc = 0.f;
        for (int r = rlo + gg; r < rhi; r += 7) acc += h[(long)r * HP + j];
        partial[gg][j] = acc;
    }
    __syncthreads();
    if (t < H) {
        float s = 0.f;
#pragma unroll
        for (int k = 0; k < 7; ++k) s += partial[k][t];
        pooled[t] = s / fmaxf((float)cntg, 1.f);
    }
    __syncthreads();
    if (t < HOUT) {
        float acc = pb[t];
#pragma unroll
        for (int k = 0; k < H; ++k) acc += pooled[k] * pW[k * HOUT + t];
        float z = fmaxf(acc, 0.f) + log1pf(expf(-fabsf(acc)));  // softplus
        float pr = z * oW[t];
#pragma unroll
        for (int off = 32; off; off >>= 1) pr += __shfl_down(pr, off);
        if (t == 0) out[g] = pr + ob[0];
    }
}

static inline int grid_for(long n, int block = 256, long cap = 2048) {
    long b = (n + block - 1) / block;
    if (b > cap) b = cap;
    if (b < 1) b = 1;
    return (int)b;
}

extern "C" void kernel_launch(void* const* d_in, const int* in_sizes, int n_in,
                              void* d_out, int out_size, void* d_ws, size_t ws_size,
                              hipStream_t stream) {
    const float* x       = (const float*)d_in[0];
    const float* he      = (const float*)d_in[1];
    const int*   ni      = (const int*)d_in[2];
    const int*   ei      = (const int*)d_in[3];
    const int*   batch   = (const int*)d_in[4];
    const float* embed_W = (const float*)d_in[5];
    const float* embed_b = (const float*)d_in[6];
    const float* lin_W   = (const float*)d_in[7];   // [L,H,H]
    const float* att     = (const float*)d_in[8];   // [L,2H]
    const float* conv_b  = (const float*)d_in[9];   // [L,H]
    const float* proj_W  = (const float*)d_in[10];  // [H,HOUT]
    const float* proj_b  = (const float*)d_in[11];
    const float* out_W   = (const float*)d_in[12];  // [HOUT,1]
    const float* out_b   = (const float*)d_in[13];
    float* out = (float*)d_out;

    const int N    = in_sizes[0] / F_IN;  // 100000
    const int E    = in_sizes[1] / H;     // 50000
    const int NINC = in_sizes[2];         // 2000000
    const int G    = out_size;            // 256

    char* w = (char*)d_ws;
    auto alloc = [&](size_t bytes) {
        char* p = w;
        w += (bytes + 255) & ~(size_t)255;
        return p;
    };
    float* h     = (float*)alloc((size_t)N * HP * 4);
    float* xl    = (float*)alloc((size_t)N * HP * 4);
    float* e_out = (float*)alloc((size_t)E * HP * 4);
    float* s_n   = (float*)alloc((size_t)N * 4);
    float* epack = (float*)alloc((size_t)E * 16);   // float4 {s_e, m, rec, -}
    float* w2    = (float*)alloc((size_t)H * 4);
    int*   ecnt  = (int*)alloc((size_t)E * 4);
    int*   eptr  = (int*)alloc((size_t)(E + 1) * 4);
    int*   ecur  = (int*)alloc((size_t)E * 4);
    int*   ncnt  = (int*)alloc((size_t)N * 4);
    int*   nptr  = (int*)alloc((size_t)(N + 1) * 4);
    int*   ncur  = (int*)alloc((size_t)N * 4);
    int*   enode = (int*)alloc((size_t)NINC * 4);
    int*   nedge = (int*)alloc((size_t)NINC * 4);
    int*   bsums = (int*)alloc((size_t)256 * 4);

    const int BLK = 256;
    int gNH  = grid_for((long)N * HP);
    int gN   = grid_for(N);
    int gE   = grid_for(E);
    int wN   = (N + NSLICE - 1) / NSLICE;
    int wE   = (E + NSLICE - 1) / NSLICE;
    int nbE  = (E + SCH - 1) / SCH;
    int nbN  = (N + SCH - 1) / SCH;

    // ---- CSR build ----
    (void)hipMemsetAsync(ncnt, 0, (size_t)N * 4, stream);
    (void)hipMemsetAsync(ecnt, 0, (size_t)E * 4, stream);
    count_sliced_kernel<<<2048, BLK, 0, stream>>>(ni, ei, ncnt, ecnt, NINC, wN, wE);
    bsum2_kernel<<<nbE + nbN, 256, 0, stream>>>(ecnt, nbE, E, ncnt, N, bsums);
    scan_bsums_kernel<<<1, 64, 0, stream>>>(bsums, nbE, nbN);
    scan_write2_kernel<<<nbE + nbN, 256, 0, stream>>>(ecnt, eptr, ecur, nbE, E,
                                                      ncnt, nptr, ncur, N, bsums, NINC);
    csr_fill_sliced_kernel<<<2048, BLK, 0, stream>>>(ni, ei, ecur, ncur, enode, nedge,
                                                     NINC, wN, wE);

    // ---- embed ----
    embed_kernel<<<gNH, BLK, 0, stream>>>(x, embed_W, embed_b, h, N);

    // ---- layers ----
    int gEdge = (E + 3) / 4;   // 1 wave per edge
    int gNode = (N + 3) / 4;   // 1 wave per node
    for (int l = 0; l < NL; ++l) {
        const float* W  = lin_W + (size_t)l * H * H;
        const float* at = att + (size_t)l * 2 * H;
        const float* b  = conv_b + (size_t)l * H;

        lin_kernel<<<gNH, BLK, 0, stream>>>(h, W, xl, N);
        rowdot_kernel<<<gN, BLK, 0, stream>>>(xl, at, s_n, N, 1);
        wfold_kernel<<<1, 64, 0, stream>>>(W, at + H, w2);
        rowdot_he_kernel<<<gE, BLK, 0, stream>>>(he, w2, epack, E, 4);  // s_e -> epack.x

        edge_pass_kernel<<<gEdge, BLK, 0, stream>>>(eptr, enode, s_n, epack, xl, e_out, E);
        node_pass_kernel<<<gNode, BLK, 0, stream>>>(nptr, nedge, s_n, epack, e_out, b, h, N);
    }

    // ---- pooling + head ----
    pool_head_kernel<<<G, BLK, 0, stream>>>(h, batch, N, proj_W, proj_b, out_W, out_b, out);
}

// Round 14
// 940.298 us; speedup vs baseline: 3.8679x; 1.0788x over previous
//
#include <hip/hip_runtime.h>
#include <hip/hip_bf16.h>
#include <hip/hip_fp16.h>
#include <limits.h>
#include <math.h>

#define F_IN 92
#define H 35
#define HP 36        // fp32 row stride (h): 144 B = 9 x float4
#define HP2 36       // fp16 row stride (xl, e_out): 72 B = 9 x 8B
#define HOUT 64
#define NL 3
#define NEG_SLOPE 0.2f
#define NSLICE 8
#define SCH 2048     // scan chunk per block (256 thr x 8)

typedef int iv4 __attribute__((ext_vector_type(4)));

// ------------------------------------------------------------------
// dense kernels
// ------------------------------------------------------------------

// h[n,j] = sum_k x[n,k] * W[k,j] + b[j]   (W: F_IN x H), h stride HP (fp32)
__global__ void embed_kernel(const float* __restrict__ x, const float* __restrict__ W,
                             const float* __restrict__ b, float* __restrict__ h, int N) {
    __shared__ float sW[F_IN * H];
    for (int t = threadIdx.x; t < F_IN * H; t += blockDim.x) sW[t] = W[t];
    __syncthreads();
    int total = N * HP;
    int stride = gridDim.x * blockDim.x;
    for (int t = blockIdx.x * blockDim.x + threadIdx.x; t < total; t += stride) {
        int n = t / HP, j = t - n * HP;
        if (j < H) {
            const float* xr = x + (long)n * F_IN;
            float acc = b[j];
#pragma unroll 4
            for (int k = 0; k < F_IN; ++k) acc += xr[k] * sW[k * H + j];
            h[t] = acc;
        } else {
            h[t] = 0.f;
        }
    }
}

// xl_h[r,j] = (half) sum_k h[r,k] * W[k,j]   (in fp32 stride HP, out fp16 stride HP2)
__global__ void lin_h_kernel(const float* __restrict__ in, const float* __restrict__ W,
                             __half* __restrict__ out, int R) {
    __shared__ float sW[H * H];
    for (int t = threadIdx.x; t < H * H; t += blockDim.x) sW[t] = W[t];
    __syncthreads();
    int total = R * HP2;
    int stride = gridDim.x * blockDim.x;
    for (int t = blockIdx.x * blockDim.x + threadIdx.x; t < total; t += stride) {
        int r = t / HP2, j = t - r * HP2;
        if (j < H) {
            const float* ir = in + (long)r * HP;
            float acc = 0.f;
#pragma unroll
            for (int k = 0; k < H; ++k) acc += ir[k] * sW[k * H + j];
            out[t] = __float2half(acc);
        } else {
            out[t] = __float2half(0.f);
        }
    }
}

// s[r] = dot(in[r,:], vec[0:H])  -> s[r*stride_out]; in fp32 stride HP
__global__ void rowdot_kernel(const float* __restrict__ in, const float* __restrict__ vec,
                              float* __restrict__ s, int R, int stride_out) {
    __shared__ float sA[H];
    for (int t = threadIdx.x; t < H; t += blockDim.x) sA[t] = vec[t];
    __syncthreads();
    int stride = gridDim.x * blockDim.x;
    for (int r = blockIdx.x * blockDim.x + threadIdx.x; r < R; r += stride) {
        const float* xr = in + (long)r * HP;
        float acc = 0.f;
#pragma unroll
        for (int k = 0; k < H; ++k) acc += xr[k] * sA[k];
        s[(long)r * stride_out] = acc;
    }
}

// he_s[r] = dot(he[r,:], vec)  (he is UNPADDED stride H from input)
__global__ void rowdot_he_kernel(const float* __restrict__ in, const float* __restrict__ vec,
                                 float* __restrict__ s, int R, int stride_out) {
    __shared__ float sA[H];
    for (int t = threadIdx.x; t < H; t += blockDim.x) sA[t] = vec[t];
    __syncthreads();
    int stride = gridDim.x * blockDim.x;
    for (int r = blockIdx.x * blockDim.x + threadIdx.x; r < R; r += stride) {
        const float* xr = in + (long)r * H;
        float acc = 0.f;
#pragma unroll
        for (int k = 0; k < H; ++k) acc += xr[k] * sA[k];
        s[(long)r * stride_out] = acc;
    }
}

// w1[k] = sum_j W[k,j]*a_n[j];  w2[k] = sum_j W[k,j]*a_e[j]
// (folds lin into the score dots: s_n = h @ w1 exactly equals (h@W)@a_n)
__global__ void wfold2_kernel(const float* __restrict__ W, const float* __restrict__ an,
                              const float* __restrict__ ae,
                              float* __restrict__ w1, float* __restrict__ w2) {
    int k = threadIdx.x;
    if (k < H) {
        float acc1 = 0.f, acc2 = 0.f;
#pragma unroll
        for (int j = 0; j < H; ++j) {
            float wkj = W[k * H + j];
            acc1 += wkj * an[j];
            acc2 += wkj * ae[j];
        }
        w1[k] = acc1;
        w2[k] = acc2;
    }
}

// ------------------------------------------------------------------
// CSR build — sliced scatter (r8) + hierarchical scan (r9), both validated
// ------------------------------------------------------------------

__global__ void count_sliced_kernel(const int* __restrict__ ni, const int* __restrict__ ei,
                                    int* __restrict__ ncnt, int* __restrict__ ecnt,
                                    int ninc, int wN, int wE) {
    int s = blockIdx.x & (NSLICE - 1);
    int loN = s * wN, hiN = loN + wN;
    int loE = s * wE, hiE = loE + wE;
    int nblk = gridDim.x >> 3;
    int bid = blockIdx.x >> 3;
    int nvec = ninc >> 2;
    int stride = nblk * blockDim.x;
    for (int q = bid * blockDim.x + threadIdx.x; q < nvec; q += stride) {
        iv4 v4 = __builtin_nontemporal_load((const iv4*)ni + q);
        iv4 e4 = __builtin_nontemporal_load((const iv4*)ei + q);
#pragma unroll
        for (int u = 0; u < 4; ++u) {
            int e = e4[u], v = v4[u];
            if (e >= loE && e < hiE) atomicAdd(&ecnt[e], 1);
            if (v >= loN && v < hiN) atomicAdd(&ncnt[v], 1);
        }
    }
    if (bid == 0) {
        for (int i = (nvec << 2) + threadIdx.x; i < ninc; i += blockDim.x) {
            int v = ni[i], e = ei[i];
            if (e >= loE && e < hiE) atomicAdd(&ecnt[e], 1);
            if (v >= loN && v < hiN) atomicAdd(&ncnt[v], 1);
        }
    }
}

__device__ __forceinline__ int wave_sum_i(int s) {
#pragma unroll
    for (int off = 32; off; off >>= 1) s += __shfl_xor(s, off);
    return s;
}

__global__ void bsum2_kernel(const int* __restrict__ cnt0, int nb0, int n0,
                             const int* __restrict__ cnt1, int n1,
                             int* __restrict__ bsums) {
    int b = blockIdx.x;
    const int* c; int n; int base;
    if (b < nb0) { c = cnt0; n = n0; base = b * SCH; }
    else         { c = cnt1; n = n1; base = (b - nb0) * SCH; }
    int t = threadIdx.x;
    int hi = base + SCH; if (hi > n) hi = n;
    int s = 0;
    for (int i = base + t; i < hi; i += 256) s += c[i];
    s = wave_sum_i(s);
    __shared__ int ws[4];
    if ((t & 63) == 0) ws[t >> 6] = s;
    __syncthreads();
    if (t == 0) bsums[b] = ws[0] + ws[1] + ws[2] + ws[3];
}

__global__ void scan_bsums_kernel(int* __restrict__ bsums, int nb0, int nb1) {
    int t = threadIdx.x;
    if (t == 0) {
        int acc = 0;
        for (int i = 0; i < nb0; ++i) { int v = bsums[i]; bsums[i] = acc; acc += v; }
    } else if (t == 1) {
        int acc = 0;
        for (int i = nb0; i < nb0 + nb1; ++i) { int v = bsums[i]; bsums[i] = acc; acc += v; }
    }
}

__global__ void scan_write2_kernel(const int* __restrict__ cnt0, int* __restrict__ ptr0,
                                   int* __restrict__ cur0, int nb0, int n0,
                                   const int* __restrict__ cnt1, int* __restrict__ ptr1,
                                   int* __restrict__ cur1, int n1,
                                   const int* __restrict__ bsums, int ninc) {
    int b = blockIdx.x;
    const int* c; int* p; int* u; int n; int base;
    if (b < nb0) { c = cnt0; p = ptr0; u = cur0; n = n0; base = b * SCH; }
    else         { c = cnt1; p = ptr1; u = cur1; n = n1; base = (b - nb0) * SCH; }
    int off = bsums[b];
    int t = threadIdx.x;
    int lo = base + t * 8;
    int vals[8];
    int s = 0;
#pragma unroll
    for (int k = 0; k < 8; ++k) {
        int i = lo + k;
        int v = (i < n) ? c[i] : 0;
        vals[k] = s;
        s += v;
    }
    __shared__ int lds[256];
    lds[t] = s;
    __syncthreads();
    for (int o2 = 1; o2 < 256; o2 <<= 1) {
        int v = (t >= o2) ? lds[t - o2] : 0;
        __syncthreads();
        lds[t] += v;
        __syncthreads();
    }
    int tbase = off + ((t == 0) ? 0 : lds[t - 1]);
#pragma unroll
    for (int k = 0; k < 8; ++k) {
        int i = lo + k;
        if (i < n) { int val = tbase + vals[k]; p[i] = val; u[i] = val; }
    }
    if (b == 0 && t == 0) { ptr0[n0] = ninc; ptr1[n1] = ninc; }
}

__global__ void csr_fill_sliced_kernel(const int* __restrict__ ni, const int* __restrict__ ei,
                                       int* __restrict__ ecur, int* __restrict__ ncur,
                                       int* __restrict__ enode, int* __restrict__ nedge,
                                       int ninc, int wN, int wE) {
    int s = blockIdx.x & (NSLICE - 1);
    int loN = s * wN, hiN = loN + wN;
    int loE = s * wE, hiE = loE + wE;
    int nblk = gridDim.x >> 3;
    int bid = blockIdx.x >> 3;
    int nvec = ninc >> 2;
    int stride = nblk * blockDim.x;
    for (int q = bid * blockDim.x + threadIdx.x; q < nvec; q += stride) {
        iv4 v4 = __builtin_nontemporal_load((const iv4*)ni + q);
        iv4 e4 = __builtin_nontemporal_load((const iv4*)ei + q);
#pragma unroll
        for (int u = 0; u < 4; ++u) {
            int e = e4[u], v = v4[u];
            if (e >= loE && e < hiE) {
                int p = atomicAdd(&ecur[e], 1);
                enode[p] = v;
            }
            if (v >= loN && v < hiN) {
                int p = atomicAdd(&ncur[v], 1);
                nedge[p] = e;
            }
        }
    }
    if (bid == 0) {
        for (int i = (nvec << 2) + threadIdx.x; i < ninc; i += blockDim.x) {
            int v = ni[i], e = ei[i];
            if (e >= loE && e < hiE) { int p = atomicAdd(&ecur[e], 1); enode[p] = v; }
            if (v >= loN && v < hiN) { int p = atomicAdd(&ncur[v], 1); nedge[p] = e; }
        }
    }
}

// ------------------------------------------------------------------
// fused sparse passes — 7 groups x 9 lanes; fp16 rows (72B = 2 cache
// lines/gather vs fp32's 3), fp32 accumulation
// ------------------------------------------------------------------

__device__ __forceinline__ float wave_max(float m) {
#pragma unroll
    for (int off = 32; off; off >>= 1) m = fmaxf(m, __shfl_xor(m, off));
    return m;
}
__device__ __forceinline__ float wave_sum(float s) {
#pragma unroll
    for (int off = 32; off; off >>= 1) s += __shfl_xor(s, off);
    return s;
}

// grouped gather-accumulate from fp16 rows (stride HP2 halves): lane l loads 8B (4 halves)
__device__ __forceinline__ void grouped_gather_h(const __half* __restrict__ src,
                                                 const float* shA, const int* shV,
                                                 int cnt, int g, int l, float4& acc) {
    if (g < 7) {
        for (int k = g; k < cnt; k += 7) {
            float ak = shA[k];
            int vk = shV[k];
            uint2 raw = ((const uint2*)(src + (size_t)vk * HP2))[l];
            __half2 h01 = *reinterpret_cast<const __half2*>(&raw.x);
            __half2 h23 = *reinterpret_cast<const __half2*>(&raw.y);
            float2 f01 = __half22float2(h01);
            float2 f23 = __half22float2(h23);
            acc.x += ak * f01.x; acc.y += ak * f01.y;
            acc.z += ak * f23.x; acc.w += ak * f23.y;
        }
    }
}

// cross-group reduce: lanes 0..8 end with the total for their col-chunk
__device__ __forceinline__ void group_reduce(float4& acc, int lane, int l) {
#pragma unroll
    for (int gg = 1; gg < 7; ++gg) {
        int src = l + 9 * gg;
        float ox = __shfl(acc.x, src);
        float oy = __shfl(acc.y, src);
        float oz = __shfl(acc.z, src);
        float ow = __shfl(acc.w, src);
        if (lane < 9) { acc.x += ox; acc.y += oy; acc.z += oz; acc.w += ow; }
    }
}

// per edge e: softmax + weighted accumulation into e_out_h[e,:] (fp16, stride HP2)
__global__ void edge_pass_kernel(const int* __restrict__ eptr, const int* __restrict__ enode,
                                 const float* __restrict__ s_n, float* __restrict__ epack,
                                 const __half* __restrict__ xl_h,
                                 __half* __restrict__ e_out_h, int E) {
    __shared__ float shA[4][64];
    __shared__ int   shV[4][64];
    int lane = threadIdx.x & 63;
    int ws = threadIdx.x >> 6;
    int g = lane / 9, l = lane - g * 9;
    int wid = (blockIdx.x * blockDim.x + threadIdx.x) >> 6;
    int nw = (gridDim.x * blockDim.x) >> 6;
    for (int e = wid; e < E; e += nw) {
        int lo = eptr[e], hi = eptr[e + 1];
        int deg = hi - lo;
        float se = epack[4 * (long)e];
        float binv = deg > 0 ? 1.f / (float)deg : 0.f;
        float4 acc = {0.f, 0.f, 0.f, 0.f};
        float mm, rec;
        if (deg <= 64) {
            int v = 0; float sc = -INFINITY;
            if (lane < deg) {
                v = enode[lo + lane];
                sc = s_n[v] + se;
                sc = sc >= 0.f ? sc : NEG_SLOPE * sc;
            }
            float m = wave_max(sc);
            mm = (m == -INFINITY) ? 0.f : m;
            float ex = (lane < deg) ? expf(sc - mm) : 0.f;
            float s = wave_sum(ex);
            rec = 1.f / (s + 1e-16f);
            shA[ws][lane] = ex * rec * binv;
            shV[ws][lane] = v;
            grouped_gather_h(xl_h, shA[ws], shV[ws], deg, g, l, acc);
        } else {
            float m = -INFINITY;
            for (int k = lo + lane; k < hi; k += 64) {
                float sc = s_n[enode[k]] + se;
                sc = sc >= 0.f ? sc : NEG_SLOPE * sc;
                m = fmaxf(m, sc);
            }
            m = wave_max(m);
            mm = (m == -INFINITY) ? 0.f : m;
            float s = 0.f;
            for (int k = lo + lane; k < hi; k += 64) {
                float sc = s_n[enode[k]] + se;
                sc = sc >= 0.f ? sc : NEG_SLOPE * sc;
                s += expf(sc - mm);
            }
            s = wave_sum(s);
            rec = 1.f / (s + 1e-16f);
            float cb = rec * binv;
            for (int base = lo; base < hi; base += 64) {
                int v = 0; float a = 0.f;
                if (base + lane < hi) {
                    v = enode[base + lane];
                    float sc = s_n[v] + se;
                    sc = sc >= 0.f ? sc : NEG_SLOPE * sc;
                    a = expf(sc - mm) * cb;
                }
                shA[ws][lane] = a;
                shV[ws][lane] = v;
                int cn = hi - base; if (cn > 64) cn = 64;
                grouped_gather_h(xl_h, shA[ws], shV[ws], cn, g, l, acc);
            }
        }
        group_reduce(acc, lane, l);
        if (lane < 9) {
            __half2 p0 = __floats2half2_rn(acc.x, acc.y);
            __half2 p1 = __floats2half2_rn(acc.z, acc.w);
            uint2 wv;
            wv.x = *reinterpret_cast<unsigned*>(&p0);
            wv.y = *reinterpret_cast<unsigned*>(&p1);
            ((uint2*)(e_out_h + (size_t)e * HP2))[lane] = wv;
        }
        if (lane == 0) { epack[4 * (long)e + 1] = mm; epack[4 * (long)e + 2] = rec; }
    }
}

// per node v: h[v,:] = Dinv * sum alpha_i * e_out_h[e_i,:] + bias   (h fp32 stride HP)
__global__ void node_pass_kernel(const int* __restrict__ nptr, const int* __restrict__ nedge,
                                 const float* __restrict__ s_n, const float* __restrict__ epack,
                                 const __half* __restrict__ e_out_h, const float* __restrict__ bias,
                                 float* __restrict__ hout, int N) {
    __shared__ float shA[4][64];
    __shared__ int   shE[4][64];
    __shared__ float sb[HP];
    if (threadIdx.x < HP) sb[threadIdx.x] = (threadIdx.x < H) ? bias[threadIdx.x] : 0.f;
    __syncthreads();
    int lane = threadIdx.x & 63;
    int ws = threadIdx.x >> 6;
    int g = lane / 9, l = lane - g * 9;
    int wid = (blockIdx.x * blockDim.x + threadIdx.x) >> 6;
    int nw = (gridDim.x * blockDim.x) >> 6;
    for (int v = wid; v < N; v += nw) {
        int lo = nptr[v], hi = nptr[v + 1];
        int deg = hi - lo;
        float dinv = deg > 0 ? 1.f / (float)deg : 0.f;
        float sn = s_n[v];
        float4 acc = {0.f, 0.f, 0.f, 0.f};
        if (deg <= 64) {
            int e = 0; float a = 0.f;
            if (lane < deg) {
                e = nedge[lo + lane];
                float4 p = ((const float4*)epack)[e];
                float sc = sn + p.x;
                sc = sc >= 0.f ? sc : NEG_SLOPE * sc;
                a = expf(sc - p.y) * p.z;
            }
            shA[ws][lane] = a;
            shE[ws][lane] = e;
            grouped_gather_h(e_out_h, shA[ws], shE[ws], deg, g, l, acc);
        } else {
            for (int base = lo; base < hi; base += 64) {
                int e = 0; float a = 0.f;
                if (base + lane < hi) {
                    e = nedge[base + lane];
                    float4 p = ((const float4*)epack)[e];
                    float sc = sn + p.x;
                    sc = sc >= 0.f ? sc : NEG_SLOPE * sc;
                    a = expf(sc - p.y) * p.z;
                }
                shA[ws][lane] = a;
                shE[ws][lane] = e;
                int cn = hi - base; if (cn > 64) cn = 64;
                grouped_gather_h(e_out_h, shA[ws], shE[ws], cn, g, l, acc);
            }
        }
        group_reduce(acc, lane, l);
        if (lane < 9) {
            float4 bb = ((const float4*)sb)[lane];
            float4 r;
            r.x = dinv * acc.x + bb.x;
            r.y = dinv * acc.y + bb.y;
            r.z = dinv * acc.z + bb.z;
            r.w = dinv * acc.w + bb.w;
            ((float4*)(hout + (size_t)v * HP))[lane] = r;
        }
    }
}

// ------------------------------------------------------------------
// fused pooling (batch sorted -> binary search) + MLP head (h stride HP)
// ------------------------------------------------------------------
__global__ void pool_head_kernel(const float* __restrict__ h, const int* __restrict__ batch,
                                 int N, const float* __restrict__ pW, const float* __restrict__ pb,
                                 const float* __restrict__ oW, const float* __restrict__ ob,
                                 float* __restrict__ out) {
    int g = blockIdx.x;
    int t = threadIdx.x;
    __shared__ int bounds[2];
    __shared__ float partial[7][H];
    __shared__ float pooled[H];
    if (t == 0) {
        int lo = 0, hi = N;
        while (lo < hi) { int mid = (lo + hi) >> 1; if (batch[mid] < g) lo = mid + 1; else hi = mid; }
        bounds[0] = lo;
        int lo2 = lo, hi2 = N;
        while (lo2 < hi2) { int mid = (lo2 + hi2) >> 1; if (batch[mid] < g + 1) lo2 = mid + 1; else hi2 = mid; }
        bounds[1] = lo2;
    }
    __syncthreads();
    int rlo = bounds[0], rhi = bounds[1];
    int cntg = rhi - rlo;
    int gg = t / H;
    int j = t - gg * H;
    if (gg < 7) {
        float acc = 0.f;
        for (int r = rlo + gg; r < rhi; r += 7) acc += h[(long)r * HP + j];
        partial[gg][j] = acc;
    }
    __syncthreads();
    if (t < H) {
        float s = 0.f;
#pragma unroll
        for (int k = 0; k < 7; ++k) s += partial[k][t];
        pooled[t] = s / fmaxf((float)cntg, 1.f);
    }
    __syncthreads();
    if (t < HOUT) {
        float acc = pb[t];
#pragma unroll
        for (int k = 0; k < H; ++k) acc += pooled[k] * pW[k * HOUT + t];
        float z = fmaxf(acc, 0.f) + log1pf(expf(-fabsf(acc)));  // softplus
        float pr = z * oW[t];
#pragma unroll
        for (int off = 32; off; off >>= 1) pr += __shfl_down(pr, off);
        if (t == 0) out[g] = pr + ob[0];
    }
}

static inline int grid_for(long n, int block = 256, long cap = 2048) {
    long b = (n + block - 1) / block;
    if (b > cap) b = cap;
    if (b < 1) b = 1;
    return (int)b;
}

extern "C" void kernel_launch(void* const* d_in, const int* in_sizes, int n_in,
                              void* d_out, int out_size, void* d_ws, size_t ws_size,
                              hipStream_t stream) {
    const float* x       = (const float*)d_in[0];
    const float* he      = (const float*)d_in[1];
    const int*   ni      = (const int*)d_in[2];
    const int*   ei      = (const int*)d_in[3];
    const int*   batch   = (const int*)d_in[4];
    const float* embed_W = (const float*)d_in[5];
    const float* embed_b = (const float*)d_in[6];
    const float* lin_W   = (const float*)d_in[7];   // [L,H,H]
    const float* att     = (const float*)d_in[8];   // [L,2H]
    const float* conv_b  = (const float*)d_in[9];   // [L,H]
    const float* proj_W  = (const float*)d_in[10];  // [H,HOUT]
    const float* proj_b  = (const float*)d_in[11];
    const float* out_W   = (const float*)d_in[12];  // [HOUT,1]
    const float* out_b   = (const float*)d_in[13];
    float* out = (float*)d_out;

    const int N    = in_sizes[0] / F_IN;  // 100000
    const int E    = in_sizes[1] / H;     // 50000
    const int NINC = in_sizes[2];         // 2000000
    const int G    = out_size;            // 256

    char* w = (char*)d_ws;
    auto alloc = [&](size_t bytes) {
        char* p = w;
        w += (bytes + 255) & ~(size_t)255;
        return p;
    };
    float*  h       = (float*)alloc((size_t)N * HP * 4);
    __half* xl_h    = (__half*)alloc((size_t)N * HP2 * 2);
    __half* e_out_h = (__half*)alloc((size_t)E * HP2 * 2);
    float*  s_n     = (float*)alloc((size_t)N * 4);
    float*  epack   = (float*)alloc((size_t)E * 16);   // float4 {s_e, m, rec, -}
    float*  w1      = (float*)alloc((size_t)H * 4);
    float*  w2      = (float*)alloc((size_t)H * 4);
    int*    ecnt    = (int*)alloc((size_t)E * 4);
    int*    eptr    = (int*)alloc((size_t)(E + 1) * 4);
    int*    ecur    = (int*)alloc((size_t)E * 4);
    int*    ncnt    = (int*)alloc((size_t)N * 4);
    int*    nptr    = (int*)alloc((size_t)(N + 1) * 4);
    int*    ncur    = (int*)alloc((size_t)N * 4);
    int*    enode   = (int*)alloc((size_t)NINC * 4);
    int*    nedge   = (int*)alloc((size_t)NINC * 4);
    int*    bsums   = (int*)alloc((size_t)256 * 4);

    const int BLK = 256;
    int gNH  = grid_for((long)N * HP);
    int gN   = grid_for(N);
    int gE   = grid_for(E);
    int wN   = (N + NSLICE - 1) / NSLICE;
    int wE   = (E + NSLICE - 1) / NSLICE;
    int nbE  = (E + SCH - 1) / SCH;
    int nbN  = (N + SCH - 1) / SCH;

    // ---- CSR build ----
    (void)hipMemsetAsync(ncnt, 0, (size_t)N * 4, stream);
    (void)hipMemsetAsync(ecnt, 0, (size_t)E * 4, stream);
    count_sliced_kernel<<<2048, BLK, 0, stream>>>(ni, ei, ncnt, ecnt, NINC, wN, wE);
    bsum2_kernel<<<nbE + nbN, 256, 0, stream>>>(ecnt, nbE, E, ncnt, N, bsums);
    scan_bsums_kernel<<<1, 64, 0, stream>>>(bsums, nbE, nbN);
    scan_write2_kernel<<<nbE + nbN, 256, 0, stream>>>(ecnt, eptr, ecur, nbE, E,
                                                      ncnt, nptr, ncur, N, bsums, NINC);
    csr_fill_sliced_kernel<<<2048, BLK, 0, stream>>>(ni, ei, ecur, ncur, enode, nedge,
                                                     NINC, wN, wE);

    // ---- embed ----
    embed_kernel<<<gNH, BLK, 0, stream>>>(x, embed_W, embed_b, h, N);

    // ---- layers ----
    int gEdge = (E + 3) / 4;   // 1 wave per edge
    int gNode = (N + 3) / 4;   // 1 wave per node
    for (int l = 0; l < NL; ++l) {
        const float* W  = lin_W + (size_t)l * H * H;
        const float* at = att + (size_t)l * 2 * H;
        const float* b  = conv_b + (size_t)l * H;

        lin_h_kernel<<<gNH, BLK, 0, stream>>>(h, W, xl_h, N);
        wfold2_kernel<<<1, 64, 0, stream>>>(W, at, at + H, w1, w2);
        rowdot_kernel<<<gN, BLK, 0, stream>>>(h, w1, s_n, N, 1);       // s_n = h @ (W@a_n)
        rowdot_he_kernel<<<gE, BLK, 0, stream>>>(he, w2, epack, E, 4); // s_e -> epack.x

        edge_pass_kernel<<<gEdge, BLK, 0, stream>>>(eptr, enode, s_n, epack, xl_h, e_out_h, E);
        node_pass_kernel<<<gNode, BLK, 0, stream>>>(nptr, nedge, s_n, epack, e_out_h, b, h, N);
    }

    // ---- pooling + head ----
    pool_head_kernel<<<G, BLK, 0, stream>>>(h, batch, N, proj_W, proj_b, out_W, out_b, out);
}